// Round 6
// baseline (173.190 us; speedup 1.0000x reference)
//
#include <hip/hip_runtime.h>
#include <hip/hip_bf16.h>

// AttnBlock: GN -> QKV 1x1conv -> attention(n=4096,d=512) -> out-proj -> +x
// R6: PIPE=2 = triple-buffered counted-vmcnt pipeline (T3/T4): per K-step
// {vmcnt(6); s_barrier; stage(kt+2); compute(kt)} - vmcnt never drains to 0
// in steady state (the 2-phase drain-0 loop caps at ~680 TF; counted vmcnt
// is the m218 lever). Applied to S, PV, VO. SWZ=4 = S-GEMM XCD map (one z
// per XCD-half; K-panel 4MB L2-resident).

typedef __attribute__((ext_vector_type(8))) short short8_t;
typedef __attribute__((ext_vector_type(4))) short short4_t;
typedef __attribute__((ext_vector_type(4))) float f32x4;

__device__ __forceinline__ void gload16(const void* g, void* l) {
  __builtin_amdgcn_global_load_lds(
      (const __attribute__((address_space(1))) void*)g,
      (__attribute__((address_space(3))) void*)l, 16, 0, 0);
}

__device__ __forceinline__ short f2bf_bits(float f) {
  __hip_bfloat16 h = __float2bfloat16(f);
  return *reinterpret_cast<short*>(&h);
}
__device__ __forceinline__ float bfbits2f(short s) {
  union { unsigned int u; float f; } c;
  c.u = ((unsigned int)(unsigned short)s) << 16;
  return c.f;
}

// ---------------------------------------------------------------------------
// NT GEMM: C[m][n] = scale * sum_k A[m][k]*B[n][k] (+bias)(+resid)
// A rows at lda, B rows at ldb (both bf16, K-contiguous). Tile: (MF*32) x 128.
// OUTF: 0 bf16 out, 1 f32 out. BIASMODE: 0 none, 1 per-row(m), 2 per-col(n).
// PIPE: 0 serial; 1 dbuf (drain at barrier); 2 triple-buf counted vmcnt.
// SWZ: 0 blockIdx 3D. 3 = flat 512 (8m x 32n x 2z, MF=2). 4 = flat 4096
//      (64m x 32n x 2z, MF=2): XCDs 0-3 z=0, 4-7 z=1; 16 m-blocks per XCD.
// ---------------------------------------------------------------------------
template<int OUTF, int BIASMODE, int RESID, int PIPE, int SWZ, int MF>
__global__ __launch_bounds__(256, 2)
void gemm_nt(const __hip_bfloat16* __restrict__ A,
             const __hip_bfloat16* __restrict__ B,
             void* __restrict__ Cv,
             const float* __restrict__ bias,
             const float* __restrict__ resid,
             float scale, int M, int N, int K,
             int lda, int ldb, int ldc,
             long long strA, long long strB, long long strC, long long strR)
{
  int bm, bn, bz;
  if (SWZ == 0) {
    bm = blockIdx.x; bn = blockIdx.y; bz = blockIdx.z;
  } else if (SWZ == 3) {
    const int b = blockIdx.x;                 // 512 blocks
    const int xcd = b & 7, slot = b >> 3;     // slot 0..63
    bm = slot & 7;
    const int panel = xcd * 8 + (slot >> 3);  // 0..63
    bn = panel & 31; bz = panel >> 5;
  } else {
    const int b = blockIdx.x;                 // 4096 blocks
    const int xcd = b & 7;
    const int s = b >> 3;                     // 0..511
    bz = xcd >> 2;
    bm = (xcd & 3) * 16 + (s & 15);           // 0..63
    bn = s >> 4;                              // 0..31
  }
  const int z = bz;
  A += (size_t)z * strA;
  B += (size_t)z * strB;

  const int tid = threadIdx.x;
  const int w = tid >> 6, l = tid & 63;
  const int wr = w >> 1, wc = w & 1;
  const int lhi = l >> 4, llo = l & 15;
  const int m0 = bm * (MF * 32), n0 = bn * 128;

  constexpr int BUFSZ = MF * 4096 + 16384;   // A tile + B tile bytes
  constexpr int NBUF = (PIPE == 2) ? 3 : (PIPE == 1) ? 2 : 1;
  constexpr int LOADS = MF + 4;              // gloads per wave per stage
  __shared__ char sm[NBUF * BUFSZ];

  f32x4 acc[MF][4] = {};

  // staging: each global_load_lds writes 64 lanes * 16B = 1KB = 8 rows of 64 bf16.
  // LDS linear; source column pre-swizzled so ds_read uses byte^((row&7)<<4).
  const int rowInCh = l >> 3;
  const int colOff = 8 * ((l & 7) ^ (rowInCh & 7));

  const __hip_bfloat16* gAr[MF];
  const __hip_bfloat16* gBr[4];
#pragma unroll
  for (int j = 0; j < MF; ++j)
    gAr[j] = A + (size_t)(m0 + w * (8 * MF) + j * 8 + rowInCh) * lda + colOff;
#pragma unroll
  for (int r = 0; r < 4; ++r)
    gBr[r] = B + (size_t)(n0 + w * 32 + r * 8 + rowInCh) * ldb + colOff;

  auto stage = [&](int kt, int buf) {
    char* sA = sm + buf * BUFSZ;
    char* sB = sA + MF * 4096;
    const int ko = kt * 64;
#pragma unroll
    for (int j = 0; j < MF; ++j)
      gload16(gAr[j] + ko, sA + (w * MF + j) * 1024);
#pragma unroll
    for (int r = 0; r < 4; ++r)
      gload16(gBr[r] + ko, sB + (w * 4 + r) * 1024);
  };

  auto compute = [&](int buf) {
    char* sA = sm + buf * BUFSZ;
    char* sB = sA + MF * 4096;
#pragma unroll
    for (int kk = 0; kk < 2; ++kk) {
      short8_t af[MF], bf[4];
#pragma unroll
      for (int m = 0; m < MF; ++m) {
        const int row = wr * (16 * MF) + m * 16 + llo;
        const int inner = ((kk * 4 + lhi) ^ (row & 7)) * 16;
        af[m] = *(const short8_t*)(sA + row * 128 + inner);
      }
#pragma unroll
      for (int n = 0; n < 4; ++n) {
        const int row = wc * 64 + n * 16 + llo;
        const int inner = ((kk * 4 + lhi) ^ (row & 7)) * 16;
        bf[n] = *(const short8_t*)(sB + row * 128 + inner);
      }
#pragma unroll
      for (int m = 0; m < MF; ++m)
#pragma unroll
        for (int n = 0; n < 4; ++n)
          acc[m][n] = __builtin_amdgcn_mfma_f32_16x16x32_bf16(af[m], bf[n], acc[m][n], 0, 0, 0);
    }
  };

  const int nkt = K >> 6;
  if (PIPE == 2) {
    // depth-2 prefetch, 3 buffers. Steady state: vmcnt(LOADS) leaves the
    // newest stage in flight across the barrier; buf kt%3 is overwritten by
    // stage(kt+3) only after the barrier following compute(kt).
    stage(0, 0);
    if (nkt > 1) stage(1, 1);
    int cur = 0;
    for (int kt = 0; kt < nkt; ++kt) {
      if (kt + 1 < nkt) {
        asm volatile("s_waitcnt vmcnt(%0)" :: "n"(LOADS) : "memory");
      } else {
        asm volatile("s_waitcnt vmcnt(0)" ::: "memory");
      }
      __builtin_amdgcn_sched_barrier(0);
      __builtin_amdgcn_s_barrier();
      __builtin_amdgcn_sched_barrier(0);
      int st = cur + 2; if (st >= 3) st -= 3;
      if (kt + 2 < nkt) stage(kt + 2, st);
      compute(cur);
      ++cur; if (cur == 3) cur = 0;
    }
  } else if (PIPE == 1) {
    stage(0, 0);
    __syncthreads();
    int cur = 0;
    for (int kt = 0; kt < nkt; ++kt) {
      if (kt + 1 < nkt) stage(kt + 1, cur ^ 1);
      compute(cur);
      __syncthreads();
      cur ^= 1;
    }
  } else {
    for (int kt = 0; kt < nkt; ++kt) {
      __syncthreads();
      stage(kt, 0);
      __syncthreads();
      compute(0);
    }
  }

  // epilogue: C/D layout col=lane&15, row=(lane>>4)*4+reg  [m89-verified]
#pragma unroll
  for (int m = 0; m < MF; ++m) {
#pragma unroll
    for (int r = 0; r < 4; ++r) {
      const int grow = m0 + wr * (16 * MF) + m * 16 + lhi * 4 + r;
#pragma unroll
      for (int n = 0; n < 4; ++n) {
        const int gcol = n0 + wc * 64 + n * 16 + llo;
        float v = acc[m][n][r] * scale;
        if (BIASMODE == 1) v += bias[grow];
        if (BIASMODE == 2) v += bias[gcol];
        const size_t idx = (size_t)z * strC + (size_t)grow * ldc + gcol;
        if (RESID) v += resid[(size_t)z * strR + (size_t)grow * ldc + gcol];
        if (OUTF == 0) ((__hip_bfloat16*)Cv)[idx] = __float2bfloat16(v);
        else           ((float*)Cv)[idx] = v;
      }
    }
  }
}

// ---------------------------------------------------------------------------
// GN stats stage A: partial sums. grid (32 groups, 16 slices, 2 z), 256 thr.
// ---------------------------------------------------------------------------
__global__ __launch_bounds__(256)
void gn_partial(const float* __restrict__ x, float* __restrict__ part)
{
  const int g = blockIdx.x, sl = blockIdx.y, z = blockIdx.z;
  const int tid = threadIdx.x;
  const float* xf = x + (size_t)z * 512 * 4096 + (size_t)g * 16 * 4096 + (size_t)sl * 4096;
  const float4* px = reinterpret_cast<const float4*>(xf);
  float s = 0.f, q = 0.f;
#pragma unroll
  for (int i = 0; i < 4; ++i) {
    float4 v = px[tid + i * 256];
    s += v.x + v.y + v.z + v.w;
    q += v.x * v.x + v.y * v.y + v.z * v.z + v.w * v.w;
  }
#pragma unroll
  for (int o = 32; o; o >>= 1) { s += __shfl_xor(s, o); q += __shfl_xor(q, o); }
  __shared__ float rs[4], rq[4];
  if ((tid & 63) == 0) { rs[tid >> 6] = s; rq[tid >> 6] = q; }
  __syncthreads();
  if (tid == 0) {
    s = rs[0] + rs[1] + rs[2] + rs[3];
    q = rq[0] + rq[1] + rq[2] + rq[3];
    part[(((size_t)z * 32 + g) * 16 + sl) * 2 + 0] = s;
    part[(((size_t)z * 32 + g) * 16 + sl) * 2 + 1] = q;
  }
}

__global__ __launch_bounds__(64)
void gn_finalize(const float* __restrict__ part, float* __restrict__ stats, int n)
{
  const int i = threadIdx.x;
  if (i >= n) return;
  float s = 0.f, q = 0.f;
#pragma unroll
  for (int sl = 0; sl < 16; ++sl) {
    s += part[(i * 16 + sl) * 2 + 0];
    q += part[(i * 16 + sl) * 2 + 1];
  }
  const float mean = s * (1.0f / 65536.0f);
  const float var = q * (1.0f / 65536.0f) - mean * mean;
  stats[i * 2 + 0] = mean;
  stats[i * 2 + 1] = rsqrtf(var + 1e-6f);
}

// ---------------------------------------------------------------------------
// Normalize + transpose: x[z][c][s] f32 -> ht[z][s][c] bf16 (64x64 LDS tiles)
// ---------------------------------------------------------------------------
__global__ __launch_bounds__(256)
void gn_apply_t(const float* __restrict__ x, const float* __restrict__ stats,
                const float* __restrict__ gns, const float* __restrict__ gnb,
                __hip_bfloat16* __restrict__ ht)
{
  const int st = blockIdx.x, ct = blockIdx.y, z = blockIdx.z;
  const int tid = threadIdx.x;
  __shared__ float tile[64][65];
  const float* xb = x + (size_t)z * 512 * 4096;
  const int lane64 = tid & 63, rr = tid >> 6;
#pragma unroll
  for (int pp = 0; pp < 16; ++pp) {
    const int cl = pp * 4 + rr;
    const int c = ct * 64 + cl;
    const int g = c >> 4;
    const float mean = stats[(z * 32 + g) * 2 + 0];
    const float rstd = stats[(z * 32 + g) * 2 + 1];
    const float val = xb[(size_t)c * 4096 + st * 64 + lane64];
    tile[cl][lane64] = (val - mean) * rstd * gns[c] + gnb[c];
  }
  __syncthreads();
  __hip_bfloat16* hb = ht + (size_t)z * 4096 * 512;
#pragma unroll
  for (int pp = 0; pp < 16; ++pp) {
    const int sl = pp * 4 + rr;
    const int s = st * 64 + sl;
    hb[(size_t)s * 512 + ct * 64 + lane64] = __float2bfloat16(tile[lane64][sl]);
  }
}

// ---------------------------------------------------------------------------
// In-place row softmax over 4096 bf16. 256 thr x 16 elems.
// ---------------------------------------------------------------------------
__global__ __launch_bounds__(256)
void softmax_rows(__hip_bfloat16* __restrict__ S, long long strZ)
{
  const int row = blockIdx.x, z = blockIdx.y;
  __hip_bfloat16* p = S + (size_t)z * strZ + (size_t)row * 4096;
  const int tid = threadIdx.x;
  short8_t a = *(const short8_t*)(p + tid * 16);
  short8_t b = *(const short8_t*)(p + tid * 16 + 8);
  float v[16];
#pragma unroll
  for (int i = 0; i < 8; ++i) { v[i] = bfbits2f(a[i]); v[8 + i] = bfbits2f(b[i]); }
  float m = v[0];
#pragma unroll
  for (int i = 1; i < 16; ++i) m = fmaxf(m, v[i]);
#pragma unroll
  for (int o = 32; o; o >>= 1) m = fmaxf(m, __shfl_xor(m, o));
  __shared__ float red[8];
  if ((tid & 63) == 0) red[tid >> 6] = m;
  __syncthreads();
  m = fmaxf(fmaxf(red[0], red[1]), fmaxf(red[2], red[3]));
  float s = 0.f;
#pragma unroll
  for (int i = 0; i < 16; ++i) { v[i] = exp2f((v[i] - m) * 1.44269504f); s += v[i]; }
#pragma unroll
  for (int o = 32; o; o >>= 1) s += __shfl_xor(s, o);
  __syncthreads();
  if ((tid & 63) == 0) red[4 + (tid >> 6)] = s;
  __syncthreads();
  s = red[4] + red[5] + red[6] + red[7];
  const float inv = 1.f / s;
#pragma unroll
  for (int i = 0; i < 8; ++i) { a[i] = f2bf_bits(v[i] * inv); b[i] = f2bf_bits(v[8 + i] * inv); }
  *(short8_t*)(p + tid * 16) = a;
  *(short8_t*)(p + tid * 16 + 8) = b;
}

// Straight casts: wq -> slot0, wk -> slot1, wo -> slot2. grid (256, 3).
__global__ __launch_bounds__(256)
void cast3(const float* __restrict__ w0, const float* __restrict__ w1,
           const float* __restrict__ w2, __hip_bfloat16* __restrict__ out)
{
  const int j = blockIdx.y;
  const float* src = (j == 0) ? w0 : (j == 1) ? w1 : w2;
  const int i = blockIdx.x * 256 + threadIdx.x;  // float4 index < 65536
  float4 v = reinterpret_cast<const float4*>(src)[i];
  short4_t o;
  o[0] = f2bf_bits(v.x); o[1] = f2bf_bits(v.y);
  o[2] = f2bf_bits(v.z); o[3] = f2bf_bits(v.w);
  *reinterpret_cast<short4_t*>((short*)out + (size_t)j * 262144 + (size_t)i * 4) = o;
}

// wv [c][i] f32 -> wvT [i][c] bf16. grid (8, 8) 64x64 tiles.
__global__ __launch_bounds__(256)
void transpose_cast(const float* __restrict__ w, __hip_bfloat16* __restrict__ wt)
{
  __shared__ float tile[64][65];
  const int ct = blockIdx.x, it = blockIdx.y;
  const int tid = threadIdx.x;
  const int lane = tid & 63, rr = tid >> 6;
#pragma unroll
  for (int p = 0; p < 16; ++p) {
    const int cl = p * 4 + rr;
    tile[cl][lane] = w[(size_t)(ct * 64 + cl) * 512 + it * 64 + lane];
  }
  __syncthreads();
#pragma unroll
  for (int p = 0; p < 16; ++p) {
    const int il = p * 4 + rr;
    wt[(size_t)(it * 64 + il) * 512 + ct * 64 + lane] = __float2bfloat16(tile[lane][il]);
  }
}

// bvo[o] = bo[o] + wo[o,:].bv ; bqk = [bq ; bk]. grid(8) x 64.
__global__ __launch_bounds__(64)
void prep_bias(const float* __restrict__ wo, const float* __restrict__ bv,
               const float* __restrict__ bo, const float* __restrict__ bq,
               const float* __restrict__ bk,
               float* __restrict__ bvo, float* __restrict__ bqk)
{
  const int o = blockIdx.x * 64 + threadIdx.x;
  const float4* row = reinterpret_cast<const float4*>(wo + (size_t)o * 512);
  const float4* b4 = reinterpret_cast<const float4*>(bv);
  float s = 0.f;
#pragma unroll 8
  for (int i = 0; i < 128; ++i) {
    float4 a = row[i], b = b4[i];
    s += a.x * b.x + a.y * b.y + a.z * b.z + a.w * b.w;
  }
  bvo[o] = s + bo[o];
  bqk[o] = bq[o];
  bqk[512 + o] = bk[o];
}

// ---------------------------------------------------------------------------
extern "C" void kernel_launch(void* const* d_in, const int* in_sizes, int n_in,
                              void* d_out, int out_size, void* d_ws, size_t ws_size,
                              hipStream_t stream)
{
  const float* x   = (const float*)d_in[0];
  const float* gns = (const float*)d_in[1];
  const float* gnb = (const float*)d_in[2];
  const float* wq  = (const float*)d_in[3];
  const float* bq  = (const float*)d_in[4];
  const float* wk  = (const float*)d_in[5];
  const float* bk  = (const float*)d_in[6];
  const float* wv  = (const float*)d_in[7];
  const float* bv  = (const float*)d_in[8];
  const float* wo  = (const float*)d_in[9];
  const float* bo  = (const float*)d_in[10];
  float* out = (float*)d_out;

  const int WB = 512 * 512;
  const long long HT  = 4096LL * 512;    // ht per-z elements
  const long long QKz = 4096LL * 1024;   // qk per-z elements
  const long long VOz = 512LL * 4096;    // vo per-z elements
  const long long SS  = 4096LL * 4096;   // S per-z elements
  const long long CHW = 512LL * 4096;

  char* base = (char*)d_ws;
  size_t off = 0;
  auto alloc = [&](size_t b) { void* r = base + off; off = (off + b + 255) & ~(size_t)255; return r; };

  // weights: [0]=wq, [1]=wk (wqk contiguous), [2]=wo, [3]=wvT, [4]=WVO
  __hip_bfloat16* wbf = (__hip_bfloat16*)alloc((size_t)5 * WB * 2);
  float* bqk   = (float*)alloc(1024 * 4);
  float* bvo   = (float*)alloc(512 * 4);
  float* part  = (float*)alloc(2 * 32 * 16 * 2 * 4);
  float* stats = (float*)alloc(2 * 32 * 2 * 4);
  const size_t fixed = off;

  const size_t qkB = (size_t)2 * QKz * 2;   // 16 MB
  const size_t voB = (size_t)2 * VOz * 2;   // 8 MB
  const size_t sB2 = (size_t)2 * SS * 2;    // 64 MB
  const size_t sB1 = (size_t)SS * 2;        // 32 MB
  const int MODE = (ws_size >= fixed + qkB + voB + sB2) ? 2 : 1;

  __hip_bfloat16* qk   = (__hip_bfloat16*)alloc(qkB);
  __hip_bfloat16* vo   = (__hip_bfloat16*)alloc(voB);
  const size_t sbufB = (MODE == 2) ? sB2 : sB1;
  __hip_bfloat16* sbuf = (__hip_bfloat16*)alloc(sbufB);
  // ht aliases the tail of sbuf: dead before S GEMM writes sbuf.
  __hip_bfloat16* ht = (__hip_bfloat16*)((char*)sbuf + sbufB - (size_t)2 * HT * 2);

  __hip_bfloat16* wqk = wbf;
  __hip_bfloat16* woB = wbf + 2 * WB;
  __hip_bfloat16* wvT = wbf + 3 * WB;
  __hip_bfloat16* wvo = wbf + 4 * WB;

  const float SC = 0.04419417382415922f;  // 512^-0.5

  cast3<<<dim3(256, 3), 256, 0, stream>>>(wq, wk, wo, wbf);
  transpose_cast<<<dim3(8, 8), 256, 0, stream>>>(wv, wvT);
  prep_bias<<<8, 64, 0, stream>>>(wo, bv, bo, bq, bk, bvo, bqk);
  gn_partial<<<dim3(32, 16, 2), 256, 0, stream>>>(x, part);
  gn_finalize<<<1, 64, 0, stream>>>(part, stats, 64);

  // WVO[o][i] = sum_c wo[o][c] * wvT[i][c]
  gemm_nt<0, 0, 0, 1, 0, 4><<<dim3(4, 4, 1), 256, 0, stream>>>(
      woB, wvT, wvo, nullptr, nullptr, 1.f, 512, 512, 512,
      512, 512, 512, 0, 0, 0, 0);

  gn_apply_t<<<dim3(64, 8, 2), 256, 0, stream>>>(x, stats, gns, gnb, ht);

  // [Q|K][s][o2] = ht . wqk^T + bqk  (o2 in 0..1024)
  gemm_nt<0, 2, 0, 1, 0, 4><<<dim3(32, 8, 2), 256, 0, stream>>>(
      ht, wqk, qk, bqk, nullptr, 1.f, 4096, 1024, 512,
      512, 512, 1024, HT, 0, QKz, 0);

  // VO[o][j] = WVO . ht^T   (64x128 tile, PIPE2, flat 512, SWZ=3)
  gemm_nt<0, 0, 0, 2, 3, 2><<<dim3(512, 1, 1), 256, 0, stream>>>(
      wvo, ht, vo, nullptr, nullptr, 1.f, 512, 4096, 512,
      512, 512, 4096, 0, HT, VOz, 0);

  if (MODE == 2) {
    // S[i][j] = (Q . K^T) * scale   (64x128, PIPE2, flat 4096, SWZ=4)
    gemm_nt<0, 0, 0, 2, 4, 2><<<dim3(4096, 1, 1), 256, 0, stream>>>(
        qk, qk + 512, sbuf, nullptr, nullptr, SC, 4096, 4096, 512,
        1024, 1024, 4096, QKz, QKz, SS, 0);
    softmax_rows<<<dim3(4096, 2), 256, 0, stream>>>(sbuf, SS);
    // out[o][i] = sum_j VO[o][j] P[i][j] + bvo[o] + x[o][i]  (PIPE2, SWZ=3)
    gemm_nt<1, 1, 1, 2, 3, 2><<<dim3(512, 1, 1), 256, 0, stream>>>(
        vo, sbuf, out, bvo, x, 1.f, 512, 4096, 4096,
        4096, 4096, 4096, VOz, SS, CHW, CHW);
  } else {
    for (int z = 0; z < 2; ++z) {
      gemm_nt<0, 0, 0, 0, 0, 4><<<dim3(32, 32, 1), 256, 0, stream>>>(
          qk + (size_t)z * QKz, qk + (size_t)z * QKz + 512, sbuf, nullptr, nullptr,
          SC, 4096, 4096, 512, 1024, 1024, 4096, 0, 0, 0, 0);
      softmax_rows<<<dim3(4096, 1), 256, 0, stream>>>(sbuf, 0);
      gemm_nt<1, 1, 1, 1, 0, 2><<<dim3(8, 32, 1), 256, 0, stream>>>(
          vo + (size_t)z * VOz, sbuf, out + (size_t)z * CHW, bvo, x + (size_t)z * CHW,
          1.f, 512, 4096, 4096, 4096, 4096, 4096, 0, 0, 0, 0);
    }
  }
}

// Round 8
// 172.319 us; speedup vs baseline: 1.0051x; 1.0051x over previous
//
#include <hip/hip_runtime.h>
#include <hip/hip_bf16.h>

// AttnBlock: GN -> QKV 1x1conv -> attention(n=4096,d=512) -> out-proj -> +x
// R8: R5 baseline (167.6us, proven) + ONE change: S GEMM replaced by an
// 8-phase 256^2 kernel (s_gemm8): 8 waves, BK=64, 2 LDS bufs (128KB),
// per-phase {vmcnt(4); ds_read; stage half-unit; barrier; setprio; 16 MFMA;
// barrier}. Ledger-verified: operands staged 4-6 phases before read; stage
// of a region issued only after the barrier following its last read.

typedef __attribute__((ext_vector_type(8))) short short8_t;
typedef __attribute__((ext_vector_type(4))) short short4_t;
typedef __attribute__((ext_vector_type(4))) float f32x4;

__device__ __forceinline__ void gload16(const void* g, void* l) {
  __builtin_amdgcn_global_load_lds(
      (const __attribute__((address_space(1))) void*)g,
      (__attribute__((address_space(3))) void*)l, 16, 0, 0);
}

__device__ __forceinline__ short f2bf_bits(float f) {
  __hip_bfloat16 h = __float2bfloat16(f);
  return *reinterpret_cast<short*>(&h);
}
__device__ __forceinline__ float bfbits2f(short s) {
  union { unsigned int u; float f; } c;
  c.u = ((unsigned int)(unsigned short)s) << 16;
  return c.f;
}

// ---------------------------------------------------------------------------
// s_gemm8: S[i][j] = scale * Q[i][:].K[j][:]   (M=N=4096, K=512)
// Q = qk rows (lda 1024), K = qk+512 rows. Out bf16 S (ldc 4096, stride SS).
// 512 thr = 8 waves (2M x 4N). Tile 256x256, BK=64, nkt=8, 4 iters x 8 phases.
// Phase (T, Mh, Nh): all 8 waves compute block-quadrant (Mh,Nh) of tile T;
// wave sub-tile 64x32 (4m x 2n frags x 2kk = 16 MFMA).
// LDS: buf b (=T&1) holds tile T: A[256][64] then B[256][64], rows 128B,
// 16B-slot s at row r holds global slot s^(r&7) (R5-proven swizzle, 0 confl).
// Stage unit = (mat, half): 128 rows, wave w rows half*128+w*16..+16,
// 2 gload16/thread. Schedule (iter i computes tiles 2i buf0, 2i+1 buf1):
//  ph1:A1(2i+1) ph2:B1(2i+1) ph3:A0(2i+2) ph4:B0(2i+2)
//  ph5:A1(2i+2) ph6:B1(2i+2) ph7:A0(2i+3) ph8:B0(2i+3)
// vmcnt(4) (<=2 units in flight) at each phase start => units >=3 phases old
// complete for all waves after the following barrier; operands are 4-6 old.
// ---------------------------------------------------------------------------
__global__ __launch_bounds__(512)
void s_gemm8(const __hip_bfloat16* __restrict__ qk,
             __hip_bfloat16* __restrict__ S, float scale)
{
  const long long QKz = 4096LL * 1024;
  const long long SS  = 4096LL * 4096;

  const int b = blockIdx.x;                 // 512 blocks: 16m x 16n x 2z
  const int bz = b >> 8;
  const int r = b & 255, xcd = r & 7, sl = r >> 3;   // sl 0..31
  const int bm = (xcd >> 1) * 4 + (sl & 3);          // 0..15
  const int bn = (xcd & 1) * 8 + (sl >> 2);          // 0..15

  const __hip_bfloat16* Aq = qk + (size_t)bz * QKz;
  const __hip_bfloat16* Bk = Aq + 512;

  const int tid = threadIdx.x;
  const int wid = tid >> 6, l = tid & 63;
  const int wrM = wid >> 2, wcN = wid & 3;
  const int lhi = l >> 4, llo = l & 15;

  __shared__ char sm[2 * 65536];            // [buf][A 32KB | B 32KB]

  f32x4 acc[2][2][4][2] = {};               // [Mh][Nh][m][n]

  // staging source (per-lane): row-in-chunk l>>3, swizzled col
  const int rIn = l >> 3;
  const int colSw = 8 * ((l & 7) ^ (rIn & 7));
  const __hip_bfloat16* gA = Aq + (size_t)(bm * 256 + rIn) * 1024 + colSw;
  const __hip_bfloat16* gB = Bk + (size_t)(bn * 256 + rIn) * 1024 + colSw;

  auto STG = [&](int mat, int half, int t) {
    const __hip_bfloat16* src = mat ? gB : gA;
    char* dst = sm + (t & 1) * 65536 + mat * 32768;
    const int rb = half * 128 + wid * 16;
    gload16(src + (size_t)rb * 1024 + t * 64, dst + rb * 128);
    gload16(src + (size_t)(rb + 8) * 1024 + t * 64, dst + (rb + 8) * 128);
  };

#define PHASE(MH, NH, RBUF, ...) do {                                         \
    asm volatile("s_waitcnt vmcnt(4)" ::: "memory");                          \
    __builtin_amdgcn_sched_barrier(0);                                        \
    short8_t af[4][2], bf[2][2];                                              \
    const char* bbA = sm + (RBUF) * 65536;                                    \
    const char* bbB = bbA + 32768;                                            \
    _Pragma("unroll") for (int m = 0; m < 4; ++m) {                           \
      const int rowA = (MH) * 128 + wrM * 64 + m * 16 + llo;                  \
      _Pragma("unroll") for (int kk = 0; kk < 2; ++kk)                        \
        af[m][kk] = *(const short8_t*)(bbA + rowA * 128 +                     \
                      (((kk * 4 + lhi) ^ (rowA & 7)) * 16));                  \
    }                                                                         \
    _Pragma("unroll") for (int n = 0; n < 2; ++n) {                           \
      const int rowB = (NH) * 128 + wcN * 32 + n * 16 + llo;                  \
      _Pragma("unroll") for (int kk = 0; kk < 2; ++kk)                        \
        bf[n][kk] = *(const short8_t*)(bbB + rowB * 128 +                     \
                      (((kk * 4 + lhi) ^ (rowB & 7)) * 16));                  \
    }                                                                         \
    __VA_ARGS__;                                                              \
    __builtin_amdgcn_sched_barrier(0);                                        \
    __builtin_amdgcn_s_barrier();                                             \
    __builtin_amdgcn_sched_barrier(0);                                        \
    __builtin_amdgcn_s_setprio(1);                                            \
    _Pragma("unroll") for (int kk = 0; kk < 2; ++kk)                          \
      _Pragma("unroll") for (int m = 0; m < 4; ++m)                           \
        _Pragma("unroll") for (int n = 0; n < 2; ++n)                         \
          acc[MH][NH][m][n] = __builtin_amdgcn_mfma_f32_16x16x32_bf16(        \
              af[m][kk], bf[n][kk], acc[MH][NH][m][n], 0, 0, 0);              \
    __builtin_amdgcn_s_setprio(0);                                            \
    __builtin_amdgcn_sched_barrier(0);                                        \
    __builtin_amdgcn_s_barrier();                                             \
    __builtin_amdgcn_sched_barrier(0);                                        \
  } while (0)

  // prologue: tiles 0 (buf0) and 1 (buf1) fully staged, then drain once
  STG(0, 0, 0); STG(1, 0, 0); STG(0, 1, 0); STG(1, 1, 0);
  STG(0, 0, 1); STG(1, 0, 1); STG(0, 1, 1); STG(1, 1, 1);
  asm volatile("s_waitcnt vmcnt(0)" ::: "memory");
  __builtin_amdgcn_sched_barrier(0);
  __builtin_amdgcn_s_barrier();
  __builtin_amdgcn_sched_barrier(0);

  for (int i = 0; i < 4; ++i) {             // nkt=8, 2 tiles/iter
    const int t1 = 2 * i + 1, t2 = 2 * i + 2, t3 = 2 * i + 3;
    PHASE(0, 0, 0, if (i >= 1) STG(0, 1, t1));   // ph1: stage A1(2i+1)->buf1
    PHASE(0, 1, 0, if (i >= 1) STG(1, 1, t1));   // ph2: B1(2i+1)->buf1
    PHASE(1, 0, 0, if (t2 < 8) STG(0, 0, t2));   // ph3: A0(2i+2)->buf0
    PHASE(1, 1, 0, if (t2 < 8) STG(1, 0, t2));   // ph4: B0(2i+2)->buf0
    PHASE(0, 0, 1, if (t2 < 8) STG(0, 1, t2));   // ph5: A1(2i+2)->buf0
    PHASE(0, 1, 1, if (t2 < 8) STG(1, 1, t2));   // ph6: B1(2i+2)->buf0
    PHASE(1, 0, 1, if (t3 < 8) STG(0, 0, t3));   // ph7: A0(2i+3)->buf1
    PHASE(1, 1, 1, if (t3 < 8) STG(1, 0, t3));   // ph8: B0(2i+3)->buf1
  }
#undef PHASE

  // epilogue: C/D layout col=lane&15, row=(lane>>4)*4+reg
  __hip_bfloat16* Sb = S + (size_t)bz * SS;
#pragma unroll
  for (int Mh = 0; Mh < 2; ++Mh)
#pragma unroll
    for (int m = 0; m < 4; ++m)
#pragma unroll
      for (int rr = 0; rr < 4; ++rr) {
        const int grow = bm * 256 + Mh * 128 + wrM * 64 + m * 16 + lhi * 4 + rr;
#pragma unroll
        for (int Nh = 0; Nh < 2; ++Nh)
#pragma unroll
          for (int n = 0; n < 2; ++n) {
            const int gcol = bn * 256 + Nh * 128 + wcN * 32 + n * 16 + llo;
            Sb[(size_t)grow * 4096 + gcol] =
                __float2bfloat16(acc[Mh][Nh][m][n][rr] * scale);
          }
      }
}

// ---------------------------------------------------------------------------
// R5-proven 4-wave NT GEMM (QK, VO, PV, WVO + MODE1 fallback).
// ---------------------------------------------------------------------------
template<int OUTF, int BIASMODE, int RESID, int PIPE, int SWZ, int MF>
__global__ __launch_bounds__(256, 2)
void gemm_nt(const __hip_bfloat16* __restrict__ A,
             const __hip_bfloat16* __restrict__ B,
             void* __restrict__ Cv,
             const float* __restrict__ bias,
             const float* __restrict__ resid,
             float scale, int M, int N, int K,
             int lda, int ldb, int ldc,
             long long strA, long long strB, long long strC, long long strR)
{
  int bm, bn, bz;
  if (SWZ == 0) {
    bm = blockIdx.x; bn = blockIdx.y; bz = blockIdx.z;
  } else if (SWZ == 2) {
    const int b = blockIdx.x;            // 2048 blocks
    bz = b >> 10;
    const int b2 = b & 1023;
    const int xcd = b2 & 7, s = b2 >> 3; // s 0..127
    bm = (xcd >> 1) * 8 + (s & 7);
    bn = (xcd & 1) * 16 + (s >> 3);
  } else {
    const int b = blockIdx.x;                 // 512 blocks (8m x 32n x 2z)
    const int xcd = b & 7, slot = b >> 3;     // slot 0..63
    bm = slot & 7;
    const int panel = xcd * 8 + (slot >> 3);  // 0..63
    bn = panel & 31; bz = panel >> 5;
  }
  const int z = bz;
  A += (size_t)z * strA;
  B += (size_t)z * strB;

  const int tid = threadIdx.x;
  const int w = tid >> 6, l = tid & 63;
  const int wr = w >> 1, wc = w & 1;
  const int lhi = l >> 4, llo = l & 15;
  const int m0 = bm * (MF * 32), n0 = bn * 128;

  constexpr int BUFSZ = MF * 4096 + 16384;
  __shared__ char sm[(PIPE ? 2 : 1) * BUFSZ];

  f32x4 acc[MF][4] = {};

  const int rowInCh = l >> 3;
  const int colOff = 8 * ((l & 7) ^ (rowInCh & 7));

  const __hip_bfloat16* gAr[MF];
  const __hip_bfloat16* gBr[4];
#pragma unroll
  for (int j = 0; j < MF; ++j)
    gAr[j] = A + (size_t)(m0 + w * (8 * MF) + j * 8 + rowInCh) * lda + colOff;
#pragma unroll
  for (int r = 0; r < 4; ++r)
    gBr[r] = B + (size_t)(n0 + w * 32 + r * 8 + rowInCh) * ldb + colOff;

  auto stage = [&](int kt, int buf) {
    char* sA = sm + buf * BUFSZ;
    char* sB = sA + MF * 4096;
    const int ko = kt * 64;
#pragma unroll
    for (int j = 0; j < MF; ++j)
      gload16(gAr[j] + ko, sA + (w * MF + j) * 1024);
#pragma unroll
    for (int r = 0; r < 4; ++r)
      gload16(gBr[r] + ko, sB + (w * 4 + r) * 1024);
  };

  auto compute = [&](int buf) {
    char* sA = sm + buf * BUFSZ;
    char* sB = sA + MF * 4096;
#pragma unroll
    for (int kk = 0; kk < 2; ++kk) {
      short8_t af[MF], bf[4];
#pragma unroll
      for (int m = 0; m < MF; ++m) {
        const int row = wr * (16 * MF) + m * 16 + llo;
        const int inner = ((kk * 4 + lhi) ^ (row & 7)) * 16;
        af[m] = *(const short8_t*)(sA + row * 128 + inner);
      }
#pragma unroll
      for (int n = 0; n < 4; ++n) {
        const int row = wc * 64 + n * 16 + llo;
        const int inner = ((kk * 4 + lhi) ^ (row & 7)) * 16;
        bf[n] = *(const short8_t*)(sB + row * 128 + inner);
      }
#pragma unroll
      for (int m = 0; m < MF; ++m)
#pragma unroll
        for (int n = 0; n < 4; ++n)
          acc[m][n] = __builtin_amdgcn_mfma_f32_16x16x32_bf16(af[m], bf[n], acc[m][n], 0, 0, 0);
    }
  };

  const int nkt = K >> 6;
  if (PIPE) {
    stage(0, 0);
    __syncthreads();
    int cur = 0;
    for (int kt = 0; kt < nkt; ++kt) {
      if (kt + 1 < nkt) stage(kt + 1, cur ^ 1);
      compute(cur);
      __syncthreads();
      cur ^= 1;
    }
  } else {
    for (int kt = 0; kt < nkt; ++kt) {
      __syncthreads();
      stage(kt, 0);
      __syncthreads();
      compute(0);
    }
  }

#pragma unroll
  for (int m = 0; m < MF; ++m) {
#pragma unroll
    for (int r = 0; r < 4; ++r) {
      const int grow = m0 + wr * (16 * MF) + m * 16 + lhi * 4 + r;
#pragma unroll
      for (int n = 0; n < 4; ++n) {
        const int gcol = n0 + wc * 64 + n * 16 + llo;
        float v = acc[m][n][r] * scale;
        if (BIASMODE == 1) v += bias[grow];
        if (BIASMODE == 2) v += bias[gcol];
        const size_t idx = (size_t)z * strC + (size_t)grow * ldc + gcol;
        if (RESID) v += resid[(size_t)z * strR + (size_t)grow * ldc + gcol];
        if (OUTF == 0) ((__hip_bfloat16*)Cv)[idx] = __float2bfloat16(v);
        else           ((float*)Cv)[idx] = v;
      }
    }
  }
}

// ---------------------------------------------------------------------------
__global__ __launch_bounds__(256)
void gn_partial(const float* __restrict__ x, float* __restrict__ part)
{
  const int g = blockIdx.x, sl = blockIdx.y, z = blockIdx.z;
  const int tid = threadIdx.x;
  const float* xf = x + (size_t)z * 512 * 4096 + (size_t)g * 16 * 4096 + (size_t)sl * 4096;
  const float4* px = reinterpret_cast<const float4*>(xf);
  float s = 0.f, q = 0.f;
#pragma unroll
  for (int i = 0; i < 4; ++i) {
    float4 v = px[tid + i * 256];
    s += v.x + v.y + v.z + v.w;
    q += v.x * v.x + v.y * v.y + v.z * v.z + v.w * v.w;
  }
#pragma unroll
  for (int o = 32; o; o >>= 1) { s += __shfl_xor(s, o); q += __shfl_xor(q, o); }
  __shared__ float rs[4], rq[4];
  if ((tid & 63) == 0) { rs[tid >> 6] = s; rq[tid >> 6] = q; }
  __syncthreads();
  if (tid == 0) {
    s = rs[0] + rs[1] + rs[2] + rs[3];
    q = rq[0] + rq[1] + rq[2] + rq[3];
    part[(((size_t)z * 32 + g) * 16 + sl) * 2 + 0] = s;
    part[(((size_t)z * 32 + g) * 16 + sl) * 2 + 1] = q;
  }
}

__global__ __launch_bounds__(64)
void gn_finalize(const float* __restrict__ part, float* __restrict__ stats, int n)
{
  const int i = threadIdx.x;
  if (i >= n) return;
  float s = 0.f, q = 0.f;
#pragma unroll
  for (int sl = 0; sl < 16; ++sl) {
    s += part[(i * 16 + sl) * 2 + 0];
    q += part[(i * 16 + sl) * 2 + 1];
  }
  const float mean = s * (1.0f / 65536.0f);
  const float var = q * (1.0f / 65536.0f) - mean * mean;
  stats[i * 2 + 0] = mean;
  stats[i * 2 + 1] = rsqrtf(var + 1e-6f);
}

__global__ __launch_bounds__(256)
void gn_apply_t(const float* __restrict__ x, const float* __restrict__ stats,
                const float* __restrict__ gns, const float* __restrict__ gnb,
                __hip_bfloat16* __restrict__ ht)
{
  const int st = blockIdx.x, ct = blockIdx.y, z = blockIdx.z;
  const int tid = threadIdx.x;
  __shared__ float tile[64][65];
  const float* xb = x + (size_t)z * 512 * 4096;
  const int lane64 = tid & 63, rr = tid >> 6;
#pragma unroll
  for (int pp = 0; pp < 16; ++pp) {
    const int cl = pp * 4 + rr;
    const int c = ct * 64 + cl;
    const int g = c >> 4;
    const float mean = stats[(z * 32 + g) * 2 + 0];
    const float rstd = stats[(z * 32 + g) * 2 + 1];
    const float val = xb[(size_t)c * 4096 + st * 64 + lane64];
    tile[cl][lane64] = (val - mean) * rstd * gns[c] + gnb[c];
  }
  __syncthreads();
  __hip_bfloat16* hb = ht + (size_t)z * 4096 * 512;
#pragma unroll
  for (int pp = 0; pp < 16; ++pp) {
    const int sl = pp * 4 + rr;
    const int s = st * 64 + sl;
    hb[(size_t)s * 512 + ct * 64 + lane64] = __float2bfloat16(tile[lane64][sl]);
  }
}

__global__ __launch_bounds__(256)
void softmax_rows(__hip_bfloat16* __restrict__ S, long long strZ)
{
  const int row = blockIdx.x, z = blockIdx.y;
  __hip_bfloat16* p = S + (size_t)z * strZ + (size_t)row * 4096;
  const int tid = threadIdx.x;
  short8_t a = *(const short8_t*)(p + tid * 16);
  short8_t b = *(const short8_t*)(p + tid * 16 + 8);
  float v[16];
#pragma unroll
  for (int i = 0; i < 8; ++i) { v[i] = bfbits2f(a[i]); v[8 + i] = bfbits2f(b[i]); }
  float m = v[0];
#pragma unroll
  for (int i = 1; i < 16; ++i) m = fmaxf(m, v[i]);
#pragma unroll
  for (int o = 32; o; o >>= 1) m = fmaxf(m, __shfl_xor(m, o));
  __shared__ float red[8];
  if ((tid & 63) == 0) red[tid >> 6] = m;
  __syncthreads();
  m = fmaxf(fmaxf(red[0], red[1]), fmaxf(red[2], red[3]));
  float s = 0.f;
#pragma unroll
  for (int i = 0; i < 16; ++i) { v[i] = exp2f((v[i] - m) * 1.44269504f); s += v[i]; }
#pragma unroll
  for (int o = 32; o; o >>= 1) s += __shfl_xor(s, o);
  __syncthreads();
  if ((tid & 63) == 0) red[4 + (tid >> 6)] = s;
  __syncthreads();
  s = red[4] + red[5] + red[6] + red[7];
  const float inv = 1.f / s;
#pragma unroll
  for (int i = 0; i < 8; ++i) { a[i] = f2bf_bits(v[i] * inv); b[i] = f2bf_bits(v[8 + i] * inv); }
  *(short8_t*)(p + tid * 16) = a;
  *(short8_t*)(p + tid * 16 + 8) = b;
}

__global__ __launch_bounds__(256)
void cast3(const float* __restrict__ w0, const float* __restrict__ w1,
           const float* __restrict__ w2, __hip_bfloat16* __restrict__ out)
{
  const int j = blockIdx.y;
  const float* src = (j == 0) ? w0 : (j == 1) ? w1 : w2;
  const int i = blockIdx.x * 256 + threadIdx.x;
  float4 v = reinterpret_cast<const float4*>(src)[i];
  short4_t o;
  o[0] = f2bf_bits(v.x); o[1] = f2bf_bits(v.y);
  o[2] = f2bf_bits(v.z); o[3] = f2bf_bits(v.w);
  *reinterpret_cast<short4_t*>((short*)out + (size_t)j * 262144 + (size_t)i * 4) = o;
}

__global__ __launch_bounds__(256)
void transpose_cast(const float* __restrict__ w, __hip_bfloat16* __restrict__ wt)
{
  __shared__ float tile[64][65];
  const int ct = blockIdx.x, it = blockIdx.y;
  const int tid = threadIdx.x;
  const int lane = tid & 63, rr = tid >> 6;
#pragma unroll
  for (int p = 0; p < 16; ++p) {
    const int cl = p * 4 + rr;
    tile[cl][lane] = w[(size_t)(ct * 64 + cl) * 512 + it * 64 + lane];
  }
  __syncthreads();
#pragma unroll
  for (int p = 0; p < 16; ++p) {
    const int il = p * 4 + rr;
    wt[(size_t)(it * 64 + il) * 512 + ct * 64 + lane] = __float2bfloat16(tile[lane][il]);
  }
}

__global__ __launch_bounds__(64)
void prep_bias(const float* __restrict__ wo, const float* __restrict__ bv,
               const float* __restrict__ bo, const float* __restrict__ bq,
               const float* __restrict__ bk,
               float* __restrict__ bvo, float* __restrict__ bqk)
{
  const int o = blockIdx.x * 64 + threadIdx.x;
  const float4* row = reinterpret_cast<const float4*>(wo + (size_t)o * 512);
  const float4* b4 = reinterpret_cast<const float4*>(bv);
  float s = 0.f;
#pragma unroll 8
  for (int i = 0; i < 128; ++i) {
    float4 a = row[i], b = b4[i];
    s += a.x * b.x + a.y * b.y + a.z * b.z + a.w * b.w;
  }
  bvo[o] = s + bo[o];
  bqk[o] = bq[o];
  bqk[512 + o] = bk[o];
}

// ---------------------------------------------------------------------------
extern "C" void kernel_launch(void* const* d_in, const int* in_sizes, int n_in,
                              void* d_out, int out_size, void* d_ws, size_t ws_size,
                              hipStream_t stream)
{
  const float* x   = (const float*)d_in[0];
  const float* gns = (const float*)d_in[1];
  const float* gnb = (const float*)d_in[2];
  const float* wq  = (const float*)d_in[3];
  const float* bq  = (const float*)d_in[4];
  const float* wk  = (const float*)d_in[5];
  const float* bk  = (const float*)d_in[6];
  const float* wv  = (const float*)d_in[7];
  const float* bv  = (const float*)d_in[8];
  const float* wo  = (const float*)d_in[9];
  const float* bo  = (const float*)d_in[10];
  float* out = (float*)d_out;

  const int WB = 512 * 512;
  const long long HT  = 4096LL * 512;
  const long long QKz = 4096LL * 1024;
  const long long VOz = 512LL * 4096;
  const long long SS  = 4096LL * 4096;
  const long long CHW = 512LL * 4096;

  char* base = (char*)d_ws;
  size_t off = 0;
  auto alloc = [&](size_t b) { void* r = base + off; off = (off + b + 255) & ~(size_t)255; return r; };

  __hip_bfloat16* wbf = (__hip_bfloat16*)alloc((size_t)5 * WB * 2);
  float* bqk   = (float*)alloc(1024 * 4);
  float* bvo   = (float*)alloc(512 * 4);
  float* part  = (float*)alloc(2 * 32 * 16 * 2 * 4);
  float* stats = (float*)alloc(2 * 32 * 2 * 4);
  const size_t fixed = off;

  const size_t qkB = (size_t)2 * QKz * 2;   // 16 MB
  const size_t voB = (size_t)2 * VOz * 2;   // 8 MB
  const size_t sB2 = (size_t)2 * SS * 2;    // 64 MB
  const size_t sB1 = (size_t)SS * 2;        // 32 MB
  const int MODE = (ws_size >= fixed + qkB + voB + sB2) ? 2 : 1;

  __hip_bfloat16* qk   = (__hip_bfloat16*)alloc(qkB);
  __hip_bfloat16* vo   = (__hip_bfloat16*)alloc(voB);
  const size_t sbufB = (MODE == 2) ? sB2 : sB1;
  __hip_bfloat16* sbuf = (__hip_bfloat16*)alloc(sbufB);
  // ht aliases the tail of sbuf: dead before S GEMM writes sbuf.
  __hip_bfloat16* ht = (__hip_bfloat16*)((char*)sbuf + sbufB - (size_t)2 * HT * 2);

  __hip_bfloat16* wqk = wbf;
  __hip_bfloat16* woB = wbf + 2 * WB;
  __hip_bfloat16* wvT = wbf + 3 * WB;
  __hip_bfloat16* wvo = wbf + 4 * WB;

  const float SC = 0.04419417382415922f;  // 512^-0.5

  cast3<<<dim3(256, 3), 256, 0, stream>>>(wq, wk, wo, wbf);
  transpose_cast<<<dim3(8, 8), 256, 0, stream>>>(wv, wvT);
  prep_bias<<<8, 64, 0, stream>>>(wo, bv, bo, bq, bk, bvo, bqk);
  gn_partial<<<dim3(32, 16, 2), 256, 0, stream>>>(x, part);
  gn_finalize<<<1, 64, 0, stream>>>(part, stats, 64);

  // WVO[o][i] = sum_c wo[o][c] * wvT[i][c]
  gemm_nt<0, 0, 0, 1, 0, 4><<<dim3(4, 4, 1), 256, 0, stream>>>(
      woB, wvT, wvo, nullptr, nullptr, 1.f, 512, 512, 512,
      512, 512, 512, 0, 0, 0, 0);

  gn_apply_t<<<dim3(64, 8, 2), 256, 0, stream>>>(x, stats, gns, gnb, ht);

  // [Q|K][s][o2] = ht . wqk^T + bqk
  gemm_nt<0, 2, 0, 1, 0, 4><<<dim3(32, 8, 2), 256, 0, stream>>>(
      ht, wqk, qk, bqk, nullptr, 1.f, 4096, 1024, 512,
      512, 512, 1024, HT, 0, QKz, 0);

  // VO[o][j] = WVO . ht^T   (64x128 tile, flat 512, SWZ=3)
  gemm_nt<0, 0, 0, 1, 3, 2><<<dim3(512, 1, 1), 256, 0, stream>>>(
      wvo, ht, vo, nullptr, nullptr, 1.f, 512, 4096, 512,
      512, 512, 4096, 0, HT, VOz, 0);

  if (MODE == 2) {
    // S[i][j] = (Q . K^T) * scale    (NEW: 8-phase 256^2 kernel)
    s_gemm8<<<512, 512, 0, stream>>>(qk, sbuf, SC);
    softmax_rows<<<dim3(4096, 2), 256, 0, stream>>>(sbuf, SS);
    // out[o][i] = sum_j VO[o][j] P[i][j] + bvo[o] + x[o][i]  (64x128, SWZ=3)
    gemm_nt<1, 1, 1, 1, 3, 2><<<dim3(512, 1, 1), 256, 0, stream>>>(
        vo, sbuf, out, bvo, x, 1.f, 512, 4096, 4096,
        4096, 4096, 4096, VOz, SS, CHW, CHW);
  } else {
    for (int z = 0; z < 2; ++z) {
      gemm_nt<0, 0, 0, 0, 0, 4><<<dim3(32, 32, 1), 256, 0, stream>>>(
          qk + (size_t)z * QKz, qk + (size_t)z * QKz + 512, sbuf, nullptr, nullptr,
          SC, 4096, 4096, 512, 1024, 1024, 4096, 0, 0, 0, 0);
      softmax_rows<<<dim3(4096, 1), 256, 0, stream>>>(sbuf, 0);
      gemm_nt<1, 1, 1, 1, 0, 2><<<dim3(8, 32, 1), 256, 0, stream>>>(
          vo + (size_t)z * VOz, sbuf, out + (size_t)z * CHW, bvo, x + (size_t)z * CHW,
          1.f, 512, 4096, 4096, 4096, 4096, 4096, 0, 0, 0, 0);
    }
  }
}

// Round 9
// 159.533 us; speedup vs baseline: 1.0856x; 1.0801x over previous
//
#include <hip/hip_runtime.h>
#include <hip/hip_bf16.h>

// AttnBlock: GN -> QKV 1x1conv -> attention(n=4096,d=512) -> out-proj -> +x
// R9: (1) s_gemm8 serpentine fragment caching (phase order 00,01,11,10;
// af cached across Nh-change, bf across Mh-change: 28 ds_reads/tile vs 48)
// + last-iter vmcnt(0) (fixes R8 tail race). (2) softmax kernel eliminated:
// s_gemm8 writes Punnorm=exp(S*scale) (|S|<<88, no max needed), rowsum_recip
// computes 1/rowsum, PV epilogue multiplies. (3) PV NORM epilogue.

typedef __attribute__((ext_vector_type(8))) short short8_t;
typedef __attribute__((ext_vector_type(4))) short short4_t;
typedef __attribute__((ext_vector_type(4))) float f32x4;

__device__ __forceinline__ void gload16(const void* g, void* l) {
  __builtin_amdgcn_global_load_lds(
      (const __attribute__((address_space(1))) void*)g,
      (__attribute__((address_space(3))) void*)l, 16, 0, 0);
}

__device__ __forceinline__ short f2bf_bits(float f) {
  __hip_bfloat16 h = __float2bfloat16(f);
  return *reinterpret_cast<short*>(&h);
}
__device__ __forceinline__ float bfbits2f(short s) {
  union { unsigned int u; float f; } c;
  c.u = ((unsigned int)(unsigned short)s) << 16;
  return c.f;
}

// ---------------------------------------------------------------------------
// s_gemm8: Punnorm[i][j] = exp2(c * Q[i][:].K[j][:])   (M=N=4096, K=512)
// 512 thr = 8 waves (2M x 4N). Tile 256x256, BK=64, nkt=8, 4 iters x 8 phases.
// Serpentine phase order per tile: (0,0)[lA+lB] (0,1)[lB] (1,1)[lA] (1,0)[lB].
// Stage schedule (iter i, t2=2i+2, t3=2i+3; one STG region per phase):
//  ph1: B0(2i+1)->buf1 [i>=1]   ph2: A0(t2)->buf0   ph3: B1(t2)->buf0
//  ph4: A1(t2)->buf0            ph5: B0(t2)->buf0   ph6: A0(t3)->buf1
//  ph7: B1(t3)->buf1            ph8: A1(t3)->buf1
// Ledger: each region staged exactly one barrier after its last LDS read;
// first read >=4 phases after stage (vmcnt(4) retires it). Last iter (i=3)
// stages only ph1 and uses vmcnt(0) everywhere (tail-drain).
// ---------------------------------------------------------------------------
__global__ __launch_bounds__(512)
void s_gemm8(const __hip_bfloat16* __restrict__ qk,
             __hip_bfloat16* __restrict__ P, float c)
{
  const long long QKz = 4096LL * 1024;
  const long long SS  = 4096LL * 4096;

  const int b = blockIdx.x;                 // 512 blocks: 16m x 16n x 2z
  const int bz = b >> 8;
  const int r = b & 255, xcd = r & 7, sl = r >> 3;
  const int bm = (xcd >> 1) * 4 + (sl & 3);
  const int bn = (xcd & 1) * 8 + (sl >> 2);

  const __hip_bfloat16* Aq = qk + (size_t)bz * QKz;
  const __hip_bfloat16* Bk = Aq + 512;

  const int tid = threadIdx.x;
  const int wid = tid >> 6, l = tid & 63;
  const int wrM = wid >> 2, wcN = wid & 3;
  const int lhi = l >> 4, llo = l & 15;

  __shared__ char sm[2 * 65536];            // [buf][A 32KB | B 32KB]

  f32x4 acc[2][2][4][2] = {};               // [Mh][Nh][m][n]
  short8_t af[4][2], bf[2][2];              // persistent fragments

  const int rIn = l >> 3;
  const int colSw = 8 * ((l & 7) ^ (rIn & 7));
  const __hip_bfloat16* gA = Aq + (size_t)(bm * 256 + rIn) * 1024 + colSw;
  const __hip_bfloat16* gB = Bk + (size_t)(bn * 256 + rIn) * 1024 + colSw;

  auto STG = [&](int mat, int half, int t) {
    const __hip_bfloat16* src = mat ? gB : gA;
    char* dst = sm + (t & 1) * 65536 + mat * 32768;
    const int rb = half * 128 + wid * 16;
    gload16(src + (size_t)rb * 1024 + t * 64, dst + rb * 128);
    gload16(src + (size_t)(rb + 8) * 1024 + t * 64, dst + (rb + 8) * 128);
  };

#define PHASE(MH, NH, RBUF, WAITN, LA, LB, ...) do {                          \
    asm volatile("s_waitcnt vmcnt(" #WAITN ")" ::: "memory");                 \
    __builtin_amdgcn_sched_barrier(0);                                        \
    const char* bbA = sm + (RBUF) * 65536;                                    \
    const char* bbB = bbA + 32768;                                            \
    if (LA) {                                                                 \
      _Pragma("unroll") for (int m = 0; m < 4; ++m) {                         \
        const int rowA = (MH) * 128 + wrM * 64 + m * 16 + llo;                \
        _Pragma("unroll") for (int kk = 0; kk < 2; ++kk)                      \
          af[m][kk] = *(const short8_t*)(bbA + rowA * 128 +                   \
                        (((kk * 4 + lhi) ^ (rowA & 7)) * 16));                \
      }                                                                       \
    }                                                                         \
    if (LB) {                                                                 \
      _Pragma("unroll") for (int n = 0; n < 2; ++n) {                         \
        const int rowB = (NH) * 128 + wcN * 32 + n * 16 + llo;                \
        _Pragma("unroll") for (int kk = 0; kk < 2; ++kk)                      \
          bf[n][kk] = *(const short8_t*)(bbB + rowB * 128 +                   \
                        (((kk * 4 + lhi) ^ (rowB & 7)) * 16));                \
      }                                                                       \
    }                                                                         \
    __VA_ARGS__;                                                              \
    __builtin_amdgcn_sched_barrier(0);                                        \
    __builtin_amdgcn_s_barrier();                                             \
    __builtin_amdgcn_sched_barrier(0);                                        \
    __builtin_amdgcn_s_setprio(1);                                            \
    _Pragma("unroll") for (int kk = 0; kk < 2; ++kk)                          \
      _Pragma("unroll") for (int m = 0; m < 4; ++m)                           \
        _Pragma("unroll") for (int n = 0; n < 2; ++n)                         \
          acc[MH][NH][m][n] = __builtin_amdgcn_mfma_f32_16x16x32_bf16(        \
              af[m][kk], bf[n][kk], acc[MH][NH][m][n], 0, 0, 0);              \
    __builtin_amdgcn_s_setprio(0);                                            \
    __builtin_amdgcn_sched_barrier(0);                                        \
    __builtin_amdgcn_s_barrier();                                             \
    __builtin_amdgcn_sched_barrier(0);                                        \
  } while (0)

  // prologue: tiles 0 (buf0) and 1 (buf1) fully staged, then drain once
  STG(0, 0, 0); STG(1, 0, 0); STG(0, 1, 0); STG(1, 1, 0);
  STG(0, 0, 1); STG(1, 0, 1); STG(0, 1, 1); STG(1, 1, 1);
  asm volatile("s_waitcnt vmcnt(0)" ::: "memory");
  __builtin_amdgcn_sched_barrier(0);
  __builtin_amdgcn_s_barrier();
  __builtin_amdgcn_sched_barrier(0);

  for (int i = 0; i < 3; ++i) {             // steady iters (tiles 0..5 + stage 2..7)
    const int t1 = 2 * i + 1, t2 = 2 * i + 2, t3 = 2 * i + 3;
    PHASE(0, 0, 0, 4, 1, 1, if (i >= 1) STG(1, 0, t1));
    PHASE(0, 1, 0, 4, 0, 1, STG(0, 0, t2));
    PHASE(1, 1, 0, 4, 1, 0, STG(1, 1, t2));
    PHASE(1, 0, 0, 4, 0, 1, STG(0, 1, t2));
    PHASE(0, 0, 1, 4, 1, 1, STG(1, 0, t2));
    PHASE(0, 1, 1, 4, 0, 1, STG(0, 0, t3));
    PHASE(1, 1, 1, 4, 1, 0, STG(1, 1, t3));
    PHASE(1, 0, 1, 4, 0, 1, STG(0, 1, t3));
  }
  {                                          // last iter: tiles 6 (buf0), 7 (buf1)
    PHASE(0, 0, 0, 0, 1, 1, STG(1, 0, 7));   // B0(7)->buf1, then full drains
    PHASE(0, 1, 0, 0, 0, 1, );
    PHASE(1, 1, 0, 0, 1, 0, );
    PHASE(1, 0, 0, 0, 0, 1, );
    PHASE(0, 0, 1, 0, 1, 1, );
    PHASE(0, 1, 1, 0, 0, 1, );
    PHASE(1, 1, 1, 0, 1, 0, );
    PHASE(1, 0, 1, 0, 0, 1, );
  }
#undef PHASE

  // epilogue: Punnorm = exp2(c * acc). C/D layout col=lane&15, row=(lane>>4)*4+reg
  __hip_bfloat16* Pb = P + (size_t)bz * SS;
#pragma unroll
  for (int Mh = 0; Mh < 2; ++Mh)
#pragma unroll
    for (int m = 0; m < 4; ++m)
#pragma unroll
      for (int rr = 0; rr < 4; ++rr) {
        const int grow = bm * 256 + Mh * 128 + wrM * 64 + m * 16 + lhi * 4 + rr;
#pragma unroll
        for (int Nh = 0; Nh < 2; ++Nh)
#pragma unroll
          for (int n = 0; n < 2; ++n) {
            const int gcol = bn * 256 + Nh * 128 + wcN * 32 + n * 16 + llo;
            Pb[(size_t)grow * 4096 + gcol] =
                __float2bfloat16(exp2f(acc[Mh][Nh][m][n][rr] * c));
          }
      }
}

// ---------------------------------------------------------------------------
// rowsum_recip: rs[z][row] = 1 / sum_j Punnorm[row][j]
// ---------------------------------------------------------------------------
__global__ __launch_bounds__(256)
void rowsum_recip(const __hip_bfloat16* __restrict__ P, float* __restrict__ rs,
                  long long strZ)
{
  const int row = blockIdx.x, z = blockIdx.y;
  const __hip_bfloat16* p = P + (size_t)z * strZ + (size_t)row * 4096;
  const int tid = threadIdx.x;
  short8_t a = *(const short8_t*)(p + tid * 16);
  short8_t bq = *(const short8_t*)(p + tid * 16 + 8);
  float s = 0.f;
#pragma unroll
  for (int i = 0; i < 8; ++i) { s += bfbits2f(a[i]); s += bfbits2f(bq[i]); }
#pragma unroll
  for (int o = 32; o; o >>= 1) s += __shfl_xor(s, o);
  __shared__ float red[4];
  if ((tid & 63) == 0) red[tid >> 6] = s;
  __syncthreads();
  if (tid == 0) {
    s = red[0] + red[1] + red[2] + red[3];
    rs[(size_t)z * 4096 + row] = 1.f / s;
  }
}

// ---------------------------------------------------------------------------
// R5-proven 4-wave NT GEMM. NORM: multiply by rnorm[z*4096+gcol] (PV MODE2).
// ---------------------------------------------------------------------------
template<int OUTF, int BIASMODE, int RESID, int PIPE, int SWZ, int MF, int NORM>
__global__ __launch_bounds__(256, 2)
void gemm_nt(const __hip_bfloat16* __restrict__ A,
             const __hip_bfloat16* __restrict__ B,
             void* __restrict__ Cv,
             const float* __restrict__ bias,
             const float* __restrict__ resid,
             const float* __restrict__ rnorm,
             float scale, int M, int N, int K,
             int lda, int ldb, int ldc,
             long long strA, long long strB, long long strC, long long strR)
{
  int bm, bn, bz;
  if (SWZ == 0) {
    bm = blockIdx.x; bn = blockIdx.y; bz = blockIdx.z;
  } else if (SWZ == 2) {
    const int b = blockIdx.x;            // 2048 blocks
    bz = b >> 10;
    const int b2 = b & 1023;
    const int xcd = b2 & 7, s = b2 >> 3;
    bm = (xcd >> 1) * 8 + (s & 7);
    bn = (xcd & 1) * 16 + (s >> 3);
  } else {
    const int b = blockIdx.x;                 // 512 blocks (8m x 32n x 2z)
    const int xcd = b & 7, slot = b >> 3;
    bm = slot & 7;
    const int panel = xcd * 8 + (slot >> 3);
    bn = panel & 31; bz = panel >> 5;
  }
  const int z = bz;
  A += (size_t)z * strA;
  B += (size_t)z * strB;

  const int tid = threadIdx.x;
  const int w = tid >> 6, l = tid & 63;
  const int wr = w >> 1, wc = w & 1;
  const int lhi = l >> 4, llo = l & 15;
  const int m0 = bm * (MF * 32), n0 = bn * 128;

  constexpr int BUFSZ = MF * 4096 + 16384;
  __shared__ char sm[(PIPE ? 2 : 1) * BUFSZ];

  f32x4 acc[MF][4] = {};

  const int rowInCh = l >> 3;
  const int colOff = 8 * ((l & 7) ^ (rowInCh & 7));

  const __hip_bfloat16* gAr[MF];
  const __hip_bfloat16* gBr[4];
#pragma unroll
  for (int j = 0; j < MF; ++j)
    gAr[j] = A + (size_t)(m0 + w * (8 * MF) + j * 8 + rowInCh) * lda + colOff;
#pragma unroll
  for (int r = 0; r < 4; ++r)
    gBr[r] = B + (size_t)(n0 + w * 32 + r * 8 + rowInCh) * ldb + colOff;

  auto stage = [&](int kt, int buf) {
    char* sA = sm + buf * BUFSZ;
    char* sB = sA + MF * 4096;
    const int ko = kt * 64;
#pragma unroll
    for (int j = 0; j < MF; ++j)
      gload16(gAr[j] + ko, sA + (w * MF + j) * 1024);
#pragma unroll
    for (int r = 0; r < 4; ++r)
      gload16(gBr[r] + ko, sB + (w * 4 + r) * 1024);
  };

  auto compute = [&](int buf) {
    char* sA = sm + buf * BUFSZ;
    char* sB = sA + MF * 4096;
#pragma unroll
    for (int kk = 0; kk < 2; ++kk) {
      short8_t af[MF], bfv[4];
#pragma unroll
      for (int m = 0; m < MF; ++m) {
        const int row = wr * (16 * MF) + m * 16 + llo;
        const int inner = ((kk * 4 + lhi) ^ (row & 7)) * 16;
        af[m] = *(const short8_t*)(sA + row * 128 + inner);
      }
#pragma unroll
      for (int n = 0; n < 4; ++n) {
        const int row = wc * 64 + n * 16 + llo;
        const int inner = ((kk * 4 + lhi) ^ (row & 7)) * 16;
        bfv[n] = *(const short8_t*)(sB + row * 128 + inner);
      }
#pragma unroll
      for (int m = 0; m < MF; ++m)
#pragma unroll
        for (int n = 0; n < 4; ++n)
          acc[m][n] = __builtin_amdgcn_mfma_f32_16x16x32_bf16(af[m], bfv[n], acc[m][n], 0, 0, 0);
    }
  };

  const int nkt = K >> 6;
  if (PIPE) {
    stage(0, 0);
    __syncthreads();
    int cur = 0;
    for (int kt = 0; kt < nkt; ++kt) {
      if (kt + 1 < nkt) stage(kt + 1, cur ^ 1);
      compute(cur);
      __syncthreads();
      cur ^= 1;
    }
  } else {
    for (int kt = 0; kt < nkt; ++kt) {
      __syncthreads();
      stage(kt, 0);
      __syncthreads();
      compute(0);
    }
  }

#pragma unroll
  for (int m = 0; m < MF; ++m) {
#pragma unroll
    for (int r = 0; r < 4; ++r) {
      const int grow = m0 + wr * (16 * MF) + m * 16 + lhi * 4 + r;
#pragma unroll
      for (int n = 0; n < 4; ++n) {
        const int gcol = n0 + wc * 64 + n * 16 + llo;
        float v = acc[m][n][r] * scale;
        if (NORM) v *= rnorm[(size_t)z * 4096 + gcol];
        if (BIASMODE == 1) v += bias[grow];
        if (BIASMODE == 2) v += bias[gcol];
        const size_t idx = (size_t)z * strC + (size_t)grow * ldc + gcol;
        if (RESID) v += resid[(size_t)z * strR + (size_t)grow * ldc + gcol];
        if (OUTF == 0) ((__hip_bfloat16*)Cv)[idx] = __float2bfloat16(v);
        else           ((float*)Cv)[idx] = v;
      }
    }
  }
}

// ---------------------------------------------------------------------------
__global__ __launch_bounds__(256)
void gn_partial(const float* __restrict__ x, float* __restrict__ part)
{
  const int g = blockIdx.x, sl = blockIdx.y, z = blockIdx.z;
  const int tid = threadIdx.x;
  const float* xf = x + (size_t)z * 512 * 4096 + (size_t)g * 16 * 4096 + (size_t)sl * 4096;
  const float4* px = reinterpret_cast<const float4*>(xf);
  float s = 0.f, q = 0.f;
#pragma unroll
  for (int i = 0; i < 4; ++i) {
    float4 v = px[tid + i * 256];
    s += v.x + v.y + v.z + v.w;
    q += v.x * v.x + v.y * v.y + v.z * v.z + v.w * v.w;
  }
#pragma unroll
  for (int o = 32; o; o >>= 1) { s += __shfl_xor(s, o); q += __shfl_xor(q, o); }
  __shared__ float rs[4], rq[4];
  if ((tid & 63) == 0) { rs[tid >> 6] = s; rq[tid >> 6] = q; }
  __syncthreads();
  if (tid == 0) {
    s = rs[0] + rs[1] + rs[2] + rs[3];
    q = rq[0] + rq[1] + rq[2] + rq[3];
    part[(((size_t)z * 32 + g) * 16 + sl) * 2 + 0] = s;
    part[(((size_t)z * 32 + g) * 16 + sl) * 2 + 1] = q;
  }
}

__global__ __launch_bounds__(64)
void gn_finalize(const float* __restrict__ part, float* __restrict__ stats, int n)
{
  const int i = threadIdx.x;
  if (i >= n) return;
  float s = 0.f, q = 0.f;
#pragma unroll
  for (int sl = 0; sl < 16; ++sl) {
    s += part[(i * 16 + sl) * 2 + 0];
    q += part[(i * 16 + sl) * 2 + 1];
  }
  const float mean = s * (1.0f / 65536.0f);
  const float var = q * (1.0f / 65536.0f) - mean * mean;
  stats[i * 2 + 0] = mean;
  stats[i * 2 + 1] = rsqrtf(var + 1e-6f);
}

__global__ __launch_bounds__(256)
void gn_apply_t(const float* __restrict__ x, const float* __restrict__ stats,
                const float* __restrict__ gns, const float* __restrict__ gnb,
                __hip_bfloat16* __restrict__ ht)
{
  const int st = blockIdx.x, ct = blockIdx.y, z = blockIdx.z;
  const int tid = threadIdx.x;
  __shared__ float tile[64][65];
  const float* xb = x + (size_t)z * 512 * 4096;
  const int lane64 = tid & 63, rr = tid >> 6;
#pragma unroll
  for (int pp = 0; pp < 16; ++pp) {
    const int cl = pp * 4 + rr;
    const int c = ct * 64 + cl;
    const int g = c >> 4;
    const float mean = stats[(z * 32 + g) * 2 + 0];
    const float rstd = stats[(z * 32 + g) * 2 + 1];
    const float val = xb[(size_t)c * 4096 + st * 64 + lane64];
    tile[cl][lane64] = (val - mean) * rstd * gns[c] + gnb[c];
  }
  __syncthreads();
  __hip_bfloat16* hb = ht + (size_t)z * 4096 * 512;
#pragma unroll
  for (int pp = 0; pp < 16; ++pp) {
    const int sl = pp * 4 + rr;
    const int s = st * 64 + sl;
    hb[(size_t)s * 512 + ct * 64 + lane64] = __float2bfloat16(tile[lane64][sl]);
  }
}

__global__ __launch_bounds__(256)
void softmax_rows(__hip_bfloat16* __restrict__ S, long long strZ)
{
  const int row = blockIdx.x, z = blockIdx.y;
  __hip_bfloat16* p = S + (size_t)z * strZ + (size_t)row * 4096;
  const int tid = threadIdx.x;
  short8_t a = *(const short8_t*)(p + tid * 16);
  short8_t b = *(const short8_t*)(p + tid * 16 + 8);
  float v[16];
#pragma unroll
  for (int i = 0; i < 8; ++i) { v[i] = bfbits2f(a[i]); v[8 + i] = bfbits2f(b[i]); }
  float m = v[0];
#pragma unroll
  for (int i = 1; i < 16; ++i) m = fmaxf(m, v[i]);
#pragma unroll
  for (int o = 32; o; o >>= 1) m = fmaxf(m, __shfl_xor(m, o));
  __shared__ float red[8];
  if ((tid & 63) == 0) red[tid >> 6] = m;
  __syncthreads();
  m = fmaxf(fmaxf(red[0], red[1]), fmaxf(red[2], red[3]));
  float s = 0.f;
#pragma unroll
  for (int i = 0; i < 16; ++i) { v[i] = exp2f((v[i] - m) * 1.44269504f); s += v[i]; }
#pragma unroll
  for (int o = 32; o; o >>= 1) s += __shfl_xor(s, o);
  __syncthreads();
  if ((tid & 63) == 0) red[4 + (tid >> 6)] = s;
  __syncthreads();
  s = red[4] + red[5] + red[6] + red[7];
  const float inv = 1.f / s;
#pragma unroll
  for (int i = 0; i < 8; ++i) { a[i] = f2bf_bits(v[i] * inv); b[i] = f2bf_bits(v[8 + i] * inv); }
  *(short8_t*)(p + tid * 16) = a;
  *(short8_t*)(p + tid * 16 + 8) = b;
}

__global__ __launch_bounds__(256)
void cast3(const float* __restrict__ w0, const float* __restrict__ w1,
           const float* __restrict__ w2, __hip_bfloat16* __restrict__ out)
{
  const int j = blockIdx.y;
  const float* src = (j == 0) ? w0 : (j == 1) ? w1 : w2;
  const int i = blockIdx.x * 256 + threadIdx.x;
  float4 v = reinterpret_cast<const float4*>(src)[i];
  short4_t o;
  o[0] = f2bf_bits(v.x); o[1] = f2bf_bits(v.y);
  o[2] = f2bf_bits(v.z); o[3] = f2bf_bits(v.w);
  *reinterpret_cast<short4_t*>((short*)out + (size_t)j * 262144 + (size_t)i * 4) = o;
}

__global__ __launch_bounds__(256)
void transpose_cast(const float* __restrict__ w, __hip_bfloat16* __restrict__ wt)
{
  __shared__ float tile[64][65];
  const int ct = blockIdx.x, it = blockIdx.y;
  const int tid = threadIdx.x;
  const int lane = tid & 63, rr = tid >> 6;
#pragma unroll
  for (int p = 0; p < 16; ++p) {
    const int cl = p * 4 + rr;
    tile[cl][lane] = w[(size_t)(ct * 64 + cl) * 512 + it * 64 + lane];
  }
  __syncthreads();
#pragma unroll
  for (int p = 0; p < 16; ++p) {
    const int il = p * 4 + rr;
    wt[(size_t)(it * 64 + il) * 512 + ct * 64 + lane] = __float2bfloat16(tile[lane][il]);
  }
}

__global__ __launch_bounds__(64)
void prep_bias(const float* __restrict__ wo, const float* __restrict__ bv,
               const float* __restrict__ bo, const float* __restrict__ bq,
               const float* __restrict__ bk,
               float* __restrict__ bvo, float* __restrict__ bqk)
{
  const int o = blockIdx.x * 64 + threadIdx.x;
  const float4* row = reinterpret_cast<const float4*>(wo + (size_t)o * 512);
  const float4* b4 = reinterpret_cast<const float4*>(bv);
  float s = 0.f;
#pragma unroll 8
  for (int i = 0; i < 128; ++i) {
    float4 a = row[i], b = b4[i];
    s += a.x * b.x + a.y * b.y + a.z * b.z + a.w * b.w;
  }
  bvo[o] = s + bo[o];
  bqk[o] = bq[o];
  bqk[512 + o] = bk[o];
}

// ---------------------------------------------------------------------------
extern "C" void kernel_launch(void* const* d_in, const int* in_sizes, int n_in,
                              void* d_out, int out_size, void* d_ws, size_t ws_size,
                              hipStream_t stream)
{
  const float* x   = (const float*)d_in[0];
  const float* gns = (const float*)d_in[1];
  const float* gnb = (const float*)d_in[2];
  const float* wq  = (const float*)d_in[3];
  const float* bq  = (const float*)d_in[4];
  const float* wk  = (const float*)d_in[5];
  const float* bk  = (const float*)d_in[6];
  const float* wv  = (const float*)d_in[7];
  const float* bv  = (const float*)d_in[8];
  const float* wo  = (const float*)d_in[9];
  const float* bo  = (const float*)d_in[10];
  float* out = (float*)d_out;

  const int WB = 512 * 512;
  const long long HT  = 4096LL * 512;
  const long long QKz = 4096LL * 1024;
  const long long VOz = 512LL * 4096;
  const long long SS  = 4096LL * 4096;
  const long long CHW = 512LL * 4096;

  char* base = (char*)d_ws;
  size_t off = 0;
  auto alloc = [&](size_t b) { void* r = base + off; off = (off + b + 255) & ~(size_t)255; return r; };

  __hip_bfloat16* wbf = (__hip_bfloat16*)alloc((size_t)5 * WB * 2);
  float* bqk   = (float*)alloc(1024 * 4);
  float* bvo   = (float*)alloc(512 * 4);
  float* part  = (float*)alloc(2 * 32 * 16 * 2 * 4);
  float* stats = (float*)alloc(2 * 32 * 2 * 4);
  float* rsum  = (float*)alloc(2 * 4096 * 4);
  const size_t fixed = off;

  const size_t qkB = (size_t)2 * QKz * 2;   // 16 MB
  const size_t voB = (size_t)2 * VOz * 2;   // 8 MB
  const size_t sB2 = (size_t)2 * SS * 2;    // 64 MB
  const size_t sB1 = (size_t)SS * 2;        // 32 MB
  const int MODE = (ws_size >= fixed + qkB + voB + sB2) ? 2 : 1;

  __hip_bfloat16* qk   = (__hip_bfloat16*)alloc(qkB);
  __hip_bfloat16* vo   = (__hip_bfloat16*)alloc(voB);
  const size_t sbufB = (MODE == 2) ? sB2 : sB1;
  __hip_bfloat16* sbuf = (__hip_bfloat16*)alloc(sbufB);
  // ht aliases the tail of sbuf: dead before S GEMM writes sbuf.
  __hip_bfloat16* ht = (__hip_bfloat16*)((char*)sbuf + sbufB - (size_t)2 * HT * 2);

  __hip_bfloat16* wqk = wbf;
  __hip_bfloat16* woB = wbf + 2 * WB;
  __hip_bfloat16* wvT = wbf + 3 * WB;
  __hip_bfloat16* wvo = wbf + 4 * WB;

  const float SC = 0.04419417382415922f;                 // 512^-0.5
  const float CEXP = SC * 1.4426950408889634f;           // for exp2

  cast3<<<dim3(256, 3), 256, 0, stream>>>(wq, wk, wo, wbf);
  transpose_cast<<<dim3(8, 8), 256, 0, stream>>>(wv, wvT);
  prep_bias<<<8, 64, 0, stream>>>(wo, bv, bo, bq, bk, bvo, bqk);
  gn_partial<<<dim3(32, 16, 2), 256, 0, stream>>>(x, part);
  gn_finalize<<<1, 64, 0, stream>>>(part, stats, 64);

  // WVO[o][i] = sum_c wo[o][c] * wvT[i][c]
  gemm_nt<0, 0, 0, 1, 0, 4, 0><<<dim3(4, 4, 1), 256, 0, stream>>>(
      woB, wvT, wvo, nullptr, nullptr, nullptr, 1.f, 512, 512, 512,
      512, 512, 512, 0, 0, 0, 0);

  gn_apply_t<<<dim3(64, 8, 2), 256, 0, stream>>>(x, stats, gns, gnb, ht);

  // [Q|K][s][o2] = ht . wqk^T + bqk
  gemm_nt<0, 2, 0, 1, 0, 4, 0><<<dim3(32, 8, 2), 256, 0, stream>>>(
      ht, wqk, qk, bqk, nullptr, nullptr, 1.f, 4096, 1024, 512,
      512, 512, 1024, HT, 0, QKz, 0);

  // VO[o][j] = WVO . ht^T   (64x128 tile, flat 512, SWZ=3)
  gemm_nt<0, 0, 0, 1, 3, 2, 0><<<dim3(512, 1, 1), 256, 0, stream>>>(
      wvo, ht, vo, nullptr, nullptr, nullptr, 1.f, 512, 4096, 512,
      512, 512, 4096, 0, HT, VOz, 0);

  if (MODE == 2) {
    // Punnorm = exp(scale * Q.K^T)   (8-phase serpentine 256^2)
    s_gemm8<<<512, 512, 0, stream>>>(qk, sbuf, CEXP);
    rowsum_recip<<<dim3(4096, 2), 256, 0, stream>>>(sbuf, rsum, SS);
    // out[o][i] = (sum_j VO[o][j] Punnorm[i][j]) * rsum[i] + bvo[o] + x[o][i]
    gemm_nt<1, 1, 1, 1, 3, 2, 1><<<dim3(512, 1, 1), 256, 0, stream>>>(
        vo, sbuf, out, bvo, x, rsum, 1.f, 512, 4096, 4096,
        4096, 4096, 4096, VOz, SS, CHW, CHW);
  } else {
    for (int z = 0; z < 2; ++z) {
      gemm_nt<0, 0, 0, 0, 0, 4, 0><<<dim3(32, 32, 1), 256, 0, stream>>>(
          qk + (size_t)z * QKz, qk + (size_t)z * QKz + 512, sbuf, nullptr, nullptr,
          nullptr, SC, 4096, 4096, 512, 1024, 1024, 4096, 0, 0, 0, 0);
      softmax_rows<<<dim3(4096, 1), 256, 0, stream>>>(sbuf, 0);
      gemm_nt<1, 1, 1, 1, 0, 2, 0><<<dim3(8, 32, 1), 256, 0, stream>>>(
          vo + (size_t)z * VOz, sbuf, out + (size_t)z * CHW, bvo, x + (size_t)z * CHW,
          nullptr, 1.f, 512, 4096, 4096, 4096, 4096, 4096, 0, 0, 0, 0);
    }
  }
}

// Round 10
// 155.991 us; speedup vs baseline: 1.1103x; 1.0227x over previous
//
#include <hip/hip_runtime.h>
#include <hip/hip_bf16.h>

// AttnBlock: GN -> QKV 1x1conv -> attention(n=4096,d=512) -> out-proj -> +x
// R10: s_gemm8 with SPARSE counted vmcnt (GSTART(6) at group starts only,
// not per-phase - m201's "vmcnt only at phases 4 and 8" pattern) + rowsum
// fused into s_gemm8 epilogue (per-block partials + rs_final), eliminating
// the 12us rowsum_recip re-read of P.

typedef __attribute__((ext_vector_type(8))) short short8_t;
typedef __attribute__((ext_vector_type(4))) short short4_t;
typedef __attribute__((ext_vector_type(4))) float f32x4;

__device__ __forceinline__ void gload16(const void* g, void* l) {
  __builtin_amdgcn_global_load_lds(
      (const __attribute__((address_space(1))) void*)g,
      (__attribute__((address_space(3))) void*)l, 16, 0, 0);
}

__device__ __forceinline__ short f2bf_bits(float f) {
  __hip_bfloat16 h = __float2bfloat16(f);
  return *reinterpret_cast<short*>(&h);
}
__device__ __forceinline__ float bfbits2f(short s) {
  union { unsigned int u; float f; } c;
  c.u = ((unsigned int)(unsigned short)s) << 16;
  return c.f;
}

// ---------------------------------------------------------------------------
// s_gemm8: Punnorm[i][j] = exp2(c * Q[i][:].K[j][:]) + per-(bn) row partials.
// 512 thr = 8 waves (2M x 4N). Tile 256x256, BK=64, nkt=8, 4 iters x 8 phases.
// Serpentine phase order: (0,0)[lA+lB] (0,1)[lB] (1,1)[lA] (1,0)[lB].
// vmcnt: ONLY at group starts (ph1/ph5): GSTART(6) leaves the 3 newest STGs
// (next tile's regions) in flight; the group's regions are >=4 STGs old =>
// complete for every wave, published by the group-start barrier. Stage
// placement (one barrier after each region's last LDS read) as R9-verified.
// Epilogue: stores exp2 values + accumulates row partials -> part2[z][bn][row].
// ---------------------------------------------------------------------------
__global__ __launch_bounds__(512)
void s_gemm8(const __hip_bfloat16* __restrict__ qk,
             __hip_bfloat16* __restrict__ P, float* __restrict__ part2,
             float c)
{
  const long long QKz = 4096LL * 1024;
  const long long SS  = 4096LL * 4096;

  const int b = blockIdx.x;                 // 512 blocks: 16m x 16n x 2z
  const int bz = b >> 8;
  const int r = b & 255, xcd = r & 7, sl = r >> 3;
  const int bm = (xcd >> 1) * 4 + (sl & 3);
  const int bn = (xcd & 1) * 8 + (sl >> 2);

  const __hip_bfloat16* Aq = qk + (size_t)bz * QKz;
  const __hip_bfloat16* Bk = Aq + 512;

  const int tid = threadIdx.x;
  const int wid = tid >> 6, l = tid & 63;
  const int wrM = wid >> 2, wcN = wid & 3;
  const int lhi = l >> 4, llo = l & 15;

  __shared__ char sm[2 * 65536];            // [buf][A 32KB | B 32KB]

  f32x4 acc[2][2][4][2] = {};               // [Mh][Nh][m][n]
  short8_t af[4][2], bf[2][2];              // persistent fragments

  const int rIn = l >> 3;
  const int colSw = 8 * ((l & 7) ^ (rIn & 7));
  const __hip_bfloat16* gA = Aq + (size_t)(bm * 256 + rIn) * 1024 + colSw;
  const __hip_bfloat16* gB = Bk + (size_t)(bn * 256 + rIn) * 1024 + colSw;

  auto STG = [&](int mat, int half, int t) {
    const __hip_bfloat16* src = mat ? gB : gA;
    char* dst = sm + (t & 1) * 65536 + mat * 32768;
    const int rb = half * 128 + wid * 16;
    gload16(src + (size_t)rb * 1024 + t * 64, dst + rb * 128);
    gload16(src + (size_t)(rb + 8) * 1024 + t * 64, dst + (rb + 8) * 128);
  };

#define GSTART(N) do {                                                        \
    asm volatile("s_waitcnt vmcnt(" #N ")" ::: "memory");                     \
    __builtin_amdgcn_sched_barrier(0);                                        \
    __builtin_amdgcn_s_barrier();                                             \
    __builtin_amdgcn_sched_barrier(0);                                        \
  } while (0)

#define PHASE(MH, NH, RBUF, LA, LB, ...) do {                                 \
    const char* bbA = sm + (RBUF) * 65536;                                    \
    const char* bbB = bbA + 32768;                                            \
    if (LA) {                                                                 \
      _Pragma("unroll") for (int m = 0; m < 4; ++m) {                         \
        const int rowA = (MH) * 128 + wrM * 64 + m * 16 + llo;                \
        _Pragma("unroll") for (int kk = 0; kk < 2; ++kk)                      \
          af[m][kk] = *(const short8_t*)(bbA + rowA * 128 +                   \
                        (((kk * 4 + lhi) ^ (rowA & 7)) * 16));                \
      }                                                                       \
    }                                                                         \
    if (LB) {                                                                 \
      _Pragma("unroll") for (int n = 0; n < 2; ++n) {                         \
        const int rowB = (NH) * 128 + wcN * 32 + n * 16 + llo;                \
        _Pragma("unroll") for (int kk = 0; kk < 2; ++kk)                      \
          bf[n][kk] = *(const short8_t*)(bbB + rowB * 128 +                   \
                        (((kk * 4 + lhi) ^ (rowB & 7)) * 16));                \
      }                                                                       \
    }                                                                         \
    __VA_ARGS__;                                                              \
    __builtin_amdgcn_sched_barrier(0);                                        \
    __builtin_amdgcn_s_barrier();                                             \
    __builtin_amdgcn_sched_barrier(0);                                        \
    __builtin_amdgcn_s_setprio(1);                                            \
    _Pragma("unroll") for (int kk = 0; kk < 2; ++kk)                          \
      _Pragma("unroll") for (int m = 0; m < 4; ++m)                           \
        _Pragma("unroll") for (int n = 0; n < 2; ++n)                         \
          acc[MH][NH][m][n] = __builtin_amdgcn_mfma_f32_16x16x32_bf16(        \
              af[m][kk], bf[n][kk], acc[MH][NH][m][n], 0, 0, 0);              \
    __builtin_amdgcn_s_setprio(0);                                            \
    __builtin_amdgcn_sched_barrier(0);                                        \
    __builtin_amdgcn_s_barrier();                                             \
    __builtin_amdgcn_sched_barrier(0);                                        \
  } while (0)

  // prologue: tiles 0 (buf0) and 1 (buf1) fully staged, then drain once
  STG(0, 0, 0); STG(1, 0, 0); STG(0, 1, 0); STG(1, 1, 0);
  STG(0, 0, 1); STG(1, 0, 1); STG(0, 1, 1); STG(1, 1, 1);
  asm volatile("s_waitcnt vmcnt(0)" ::: "memory");
  __builtin_amdgcn_sched_barrier(0);
  __builtin_amdgcn_s_barrier();
  __builtin_amdgcn_sched_barrier(0);

  for (int i = 0; i < 3; ++i) {             // steady iters
    const int t1 = 2 * i + 1, t2 = 2 * i + 2, t3 = 2 * i + 3;
    GSTART(6);
    PHASE(0, 0, 0, 1, 1, if (i >= 1) STG(1, 0, t1));
    PHASE(0, 1, 0, 0, 1, STG(0, 0, t2));
    PHASE(1, 1, 0, 1, 0, STG(1, 1, t2));
    PHASE(1, 0, 0, 0, 1, STG(0, 1, t2));
    GSTART(6);
    PHASE(0, 0, 1, 1, 1, STG(1, 0, t2));
    PHASE(0, 1, 1, 0, 1, STG(0, 0, t3));
    PHASE(1, 1, 1, 1, 0, STG(1, 1, t3));
    PHASE(1, 0, 1, 0, 1, STG(0, 1, t3));
  }
  {                                          // last iter: tiles 6 (buf0), 7 (buf1)
    GSTART(6);                               // buf0 t6 regions not among 6 newest
    PHASE(0, 0, 0, 1, 1, STG(1, 0, 7));
    PHASE(0, 1, 0, 0, 1, );
    PHASE(1, 1, 0, 1, 0, );
    PHASE(1, 0, 0, 0, 1, );
    GSTART(0);                               // drain: buf1 t7 fully landed
    PHASE(0, 0, 1, 1, 1, );
    PHASE(0, 1, 1, 0, 1, );
    PHASE(1, 1, 1, 1, 0, );
    PHASE(1, 0, 1, 0, 1, );
  }
#undef PHASE
#undef GSTART

  // epilogue: store exp2 + row partials. C/D: col=lane&15, row=(lane>>4)*4+reg
  __hip_bfloat16* Pb = P + (size_t)bz * SS;
  float rp[2][4][4];                        // [Mh][m][rr] per-lane row partial
#pragma unroll
  for (int Mh = 0; Mh < 2; ++Mh)
#pragma unroll
    for (int m = 0; m < 4; ++m)
#pragma unroll
      for (int rr = 0; rr < 4; ++rr) {
        const int grow = bm * 256 + Mh * 128 + wrM * 64 + m * 16 + lhi * 4 + rr;
        float s = 0.f;
#pragma unroll
        for (int Nh = 0; Nh < 2; ++Nh)
#pragma unroll
          for (int n = 0; n < 2; ++n) {
            const int gcol = bn * 256 + Nh * 128 + wcN * 32 + n * 16 + llo;
            const float v = exp2f(acc[Mh][Nh][m][n][rr] * c);
            Pb[(size_t)grow * 4096 + gcol] = __float2bfloat16(v);
            s += v;
          }
        rp[Mh][m][rr] = s;
      }
  // reduce across llo (lane bits 0..3)
#pragma unroll
  for (int Mh = 0; Mh < 2; ++Mh)
#pragma unroll
    for (int m = 0; m < 4; ++m)
#pragma unroll
      for (int rr = 0; rr < 4; ++rr) {
        float s = rp[Mh][m][rr];
        s += __shfl_xor(s, 1); s += __shfl_xor(s, 2);
        s += __shfl_xor(s, 4); s += __shfl_xor(s, 8);
        rp[Mh][m][rr] = s;
      }
  __syncthreads();                          // safe to reuse sm
  float* rsl = (float*)sm;                  // [256][4]
  if (llo == 0) {
#pragma unroll
    for (int Mh = 0; Mh < 2; ++Mh)
#pragma unroll
      for (int m = 0; m < 4; ++m)
#pragma unroll
        for (int rr = 0; rr < 4; ++rr) {
          const int rl = Mh * 128 + wrM * 64 + m * 16 + lhi * 4 + rr;
          rsl[rl * 4 + wcN] = rp[Mh][m][rr];
        }
  }
  __syncthreads();
  if (tid < 256) {
    const float s = rsl[tid * 4] + rsl[tid * 4 + 1] + rsl[tid * 4 + 2] + rsl[tid * 4 + 3];
    part2[((size_t)bz * 16 + bn) * 4096 + bm * 256 + tid] = s;
  }
}

// rs[z][row] = 1 / sum_bn part2[z][bn][row].  8192 threads.
__global__ __launch_bounds__(256)
void rs_final(const float* __restrict__ part2, float* __restrict__ rs)
{
  const int i = blockIdx.x * 256 + threadIdx.x;  // 0..8191
  const int z = i >> 12, row = i & 4095;
  float s = 0.f;
#pragma unroll
  for (int bn = 0; bn < 16; ++bn)
    s += part2[((size_t)z * 16 + bn) * 4096 + row];
  rs[(size_t)z * 4096 + row] = 1.f / s;
}

// ---------------------------------------------------------------------------
// R5-proven 4-wave NT GEMM. NORM: multiply by rnorm[z*4096+gcol] (PV MODE2).
// ---------------------------------------------------------------------------
template<int OUTF, int BIASMODE, int RESID, int PIPE, int SWZ, int MF, int NORM>
__global__ __launch_bounds__(256, 2)
void gemm_nt(const __hip_bfloat16* __restrict__ A,
             const __hip_bfloat16* __restrict__ B,
             void* __restrict__ Cv,
             const float* __restrict__ bias,
             const float* __restrict__ resid,
             const float* __restrict__ rnorm,
             float scale, int M, int N, int K,
             int lda, int ldb, int ldc,
             long long strA, long long strB, long long strC, long long strR)
{
  int bm, bn, bz;
  if (SWZ == 0) {
    bm = blockIdx.x; bn = blockIdx.y; bz = blockIdx.z;
  } else if (SWZ == 2) {
    const int b = blockIdx.x;            // 2048 blocks
    bz = b >> 10;
    const int b2 = b & 1023;
    const int xcd = b2 & 7, s = b2 >> 3;
    bm = (xcd >> 1) * 8 + (s & 7);
    bn = (xcd & 1) * 16 + (s >> 3);
  } else {
    const int b = blockIdx.x;                 // 512 blocks (8m x 32n x 2z)
    const int xcd = b & 7, slot = b >> 3;
    bm = slot & 7;
    const int panel = xcd * 8 + (slot >> 3);
    bn = panel & 31; bz = panel >> 5;
  }
  const int z = bz;
  A += (size_t)z * strA;
  B += (size_t)z * strB;

  const int tid = threadIdx.x;
  const int w = tid >> 6, l = tid & 63;
  const int wr = w >> 1, wc = w & 1;
  const int lhi = l >> 4, llo = l & 15;
  const int m0 = bm * (MF * 32), n0 = bn * 128;

  constexpr int BUFSZ = MF * 4096 + 16384;
  __shared__ char sm[(PIPE ? 2 : 1) * BUFSZ];

  f32x4 acc[MF][4] = {};

  const int rowInCh = l >> 3;
  const int colOff = 8 * ((l & 7) ^ (rowInCh & 7));

  const __hip_bfloat16* gAr[MF];
  const __hip_bfloat16* gBr[4];
#pragma unroll
  for (int j = 0; j < MF; ++j)
    gAr[j] = A + (size_t)(m0 + w * (8 * MF) + j * 8 + rowInCh) * lda + colOff;
#pragma unroll
  for (int r = 0; r < 4; ++r)
    gBr[r] = B + (size_t)(n0 + w * 32 + r * 8 + rowInCh) * ldb + colOff;

  auto stage = [&](int kt, int buf) {
    char* sA = sm + buf * BUFSZ;
    char* sB = sA + MF * 4096;
    const int ko = kt * 64;
#pragma unroll
    for (int j = 0; j < MF; ++j)
      gload16(gAr[j] + ko, sA + (w * MF + j) * 1024);
#pragma unroll
    for (int r = 0; r < 4; ++r)
      gload16(gBr[r] + ko, sB + (w * 4 + r) * 1024);
  };

  auto compute = [&](int buf) {
    char* sA = sm + buf * BUFSZ;
    char* sB = sA + MF * 4096;
#pragma unroll
    for (int kk = 0; kk < 2; ++kk) {
      short8_t af[MF], bfv[4];
#pragma unroll
      for (int m = 0; m < MF; ++m) {
        const int row = wr * (16 * MF) + m * 16 + llo;
        const int inner = ((kk * 4 + lhi) ^ (row & 7)) * 16;
        af[m] = *(const short8_t*)(sA + row * 128 + inner);
      }
#pragma unroll
      for (int n = 0; n < 4; ++n) {
        const int row = wc * 64 + n * 16 + llo;
        const int inner = ((kk * 4 + lhi) ^ (row & 7)) * 16;
        bfv[n] = *(const short8_t*)(sB + row * 128 + inner);
      }
#pragma unroll
      for (int m = 0; m < MF; ++m)
#pragma unroll
        for (int n = 0; n < 4; ++n)
          acc[m][n] = __builtin_amdgcn_mfma_f32_16x16x32_bf16(af[m], bfv[n], acc[m][n], 0, 0, 0);
    }
  };

  const int nkt = K >> 6;
  if (PIPE) {
    stage(0, 0);
    __syncthreads();
    int cur = 0;
    for (int kt = 0; kt < nkt; ++kt) {
      if (kt + 1 < nkt) stage(kt + 1, cur ^ 1);
      compute(cur);
      __syncthreads();
      cur ^= 1;
    }
  } else {
    for (int kt = 0; kt < nkt; ++kt) {
      __syncthreads();
      stage(kt, 0);
      __syncthreads();
      compute(0);
    }
  }

#pragma unroll
  for (int m = 0; m < MF; ++m) {
#pragma unroll
    for (int r = 0; r < 4; ++r) {
      const int grow = m0 + wr * (16 * MF) + m * 16 + lhi * 4 + r;
#pragma unroll
      for (int n = 0; n < 4; ++n) {
        const int gcol = n0 + wc * 64 + n * 16 + llo;
        float v = acc[m][n][r] * scale;
        if (NORM) v *= rnorm[(size_t)z * 4096 + gcol];
        if (BIASMODE == 1) v += bias[grow];
        if (BIASMODE == 2) v += bias[gcol];
        const size_t idx = (size_t)z * strC + (size_t)grow * ldc + gcol;
        if (RESID) v += resid[(size_t)z * strR + (size_t)grow * ldc + gcol];
        if (OUTF == 0) ((__hip_bfloat16*)Cv)[idx] = __float2bfloat16(v);
        else           ((float*)Cv)[idx] = v;
      }
    }
  }
}

// ---------------------------------------------------------------------------
__global__ __launch_bounds__(256)
void gn_partial(const float* __restrict__ x, float* __restrict__ part)
{
  const int g = blockIdx.x, sl = blockIdx.y, z = blockIdx.z;
  const int tid = threadIdx.x;
  const float* xf = x + (size_t)z * 512 * 4096 + (size_t)g * 16 * 4096 + (size_t)sl * 4096;
  const float4* px = reinterpret_cast<const float4*>(xf);
  float s = 0.f, q = 0.f;
#pragma unroll
  for (int i = 0; i < 4; ++i) {
    float4 v = px[tid + i * 256];
    s += v.x + v.y + v.z + v.w;
    q += v.x * v.x + v.y * v.y + v.z * v.z + v.w * v.w;
  }
#pragma unroll
  for (int o = 32; o; o >>= 1) { s += __shfl_xor(s, o); q += __shfl_xor(q, o); }
  __shared__ float rs[4], rq[4];
  if ((tid & 63) == 0) { rs[tid >> 6] = s; rq[tid >> 6] = q; }
  __syncthreads();
  if (tid == 0) {
    s = rs[0] + rs[1] + rs[2] + rs[3];
    q = rq[0] + rq[1] + rq[2] + rq[3];
    part[(((size_t)z * 32 + g) * 16 + sl) * 2 + 0] = s;
    part[(((size_t)z * 32 + g) * 16 + sl) * 2 + 1] = q;
  }
}

__global__ __launch_bounds__(64)
void gn_finalize(const float* __restrict__ part, float* __restrict__ stats, int n)
{
  const int i = threadIdx.x;
  if (i >= n) return;
  float s = 0.f, q = 0.f;
#pragma unroll
  for (int sl = 0; sl < 16; ++sl) {
    s += part[(i * 16 + sl) * 2 + 0];
    q += part[(i * 16 + sl) * 2 + 1];
  }
  const float mean = s * (1.0f / 65536.0f);
  const float var = q * (1.0f / 65536.0f) - mean * mean;
  stats[i * 2 + 0] = mean;
  stats[i * 2 + 1] = rsqrtf(var + 1e-6f);
}

__global__ __launch_bounds__(256)
void gn_apply_t(const float* __restrict__ x, const float* __restrict__ stats,
                const float* __restrict__ gns, const float* __restrict__ gnb,
                __hip_bfloat16* __restrict__ ht)
{
  const int st = blockIdx.x, ct = blockIdx.y, z = blockIdx.z;
  const int tid = threadIdx.x;
  __shared__ float tile[64][65];
  const float* xb = x + (size_t)z * 512 * 4096;
  const int lane64 = tid & 63, rr = tid >> 6;
#pragma unroll
  for (int pp = 0; pp < 16; ++pp) {
    const int cl = pp * 4 + rr;
    const int c = ct * 64 + cl;
    const int g = c >> 4;
    const float mean = stats[(z * 32 + g) * 2 + 0];
    const float rstd = stats[(z * 32 + g) * 2 + 1];
    const float val = xb[(size_t)c * 4096 + st * 64 + lane64];
    tile[cl][lane64] = (val - mean) * rstd * gns[c] + gnb[c];
  }
  __syncthreads();
  __hip_bfloat16* hb = ht + (size_t)z * 4096 * 512;
#pragma unroll
  for (int pp = 0; pp < 16; ++pp) {
    const int sl = pp * 4 + rr;
    const int s = st * 64 + sl;
    hb[(size_t)s * 512 + ct * 64 + lane64] = __float2bfloat16(tile[lane64][sl]);
  }
}

__global__ __launch_bounds__(256)
void softmax_rows(__hip_bfloat16* __restrict__ S, long long strZ)
{
  const int row = blockIdx.x, z = blockIdx.y;
  __hip_bfloat16* p = S + (size_t)z * strZ + (size_t)row * 4096;
  const int tid = threadIdx.x;
  short8_t a = *(const short8_t*)(p + tid * 16);
  short8_t b = *(const short8_t*)(p + tid * 16 + 8);
  float v[16];
#pragma unroll
  for (int i = 0; i < 8; ++i) { v[i] = bfbits2f(a[i]); v[8 + i] = bfbits2f(b[i]); }
  float m = v[0];
#pragma unroll
  for (int i = 1; i < 16; ++i) m = fmaxf(m, v[i]);
#pragma unroll
  for (int o = 32; o; o >>= 1) m = fmaxf(m, __shfl_xor(m, o));
  __shared__ float red[8];
  if ((tid & 63) == 0) red[tid >> 6] = m;
  __syncthreads();
  m = fmaxf(fmaxf(red[0], red[1]), fmaxf(red[2], red[3]));
  float s = 0.f;
#pragma unroll
  for (int i = 0; i < 16; ++i) { v[i] = exp2f((v[i] - m) * 1.44269504f); s += v[i]; }
#pragma unroll
  for (int o = 32; o; o >>= 1) s += __shfl_xor(s, o);
  __syncthreads();
  if ((tid & 63) == 0) red[4 + (tid >> 6)] = s;
  __syncthreads();
  s = red[4] + red[5] + red[6] + red[7];
  const float inv = 1.f / s;
#pragma unroll
  for (int i = 0; i < 8; ++i) { a[i] = f2bf_bits(v[i] * inv); b[i] = f2bf_bits(v[8 + i] * inv); }
  *(short8_t*)(p + tid * 16) = a;
  *(short8_t*)(p + tid * 16 + 8) = b;
}

__global__ __launch_bounds__(256)
void cast3(const float* __restrict__ w0, const float* __restrict__ w1,
           const float* __restrict__ w2, __hip_bfloat16* __restrict__ out)
{
  const int j = blockIdx.y;
  const float* src = (j == 0) ? w0 : (j == 1) ? w1 : w2;
  const int i = blockIdx.x * 256 + threadIdx.x;
  float4 v = reinterpret_cast<const float4*>(src)[i];
  short4_t o;
  o[0] = f2bf_bits(v.x); o[1] = f2bf_bits(v.y);
  o[2] = f2bf_bits(v.z); o[3] = f2bf_bits(v.w);
  *reinterpret_cast<short4_t*>((short*)out + (size_t)j * 262144 + (size_t)i * 4) = o;
}

__global__ __launch_bounds__(256)
void transpose_cast(const float* __restrict__ w, __hip_bfloat16* __restrict__ wt)
{
  __shared__ float tile[64][65];
  const int ct = blockIdx.x, it = blockIdx.y;
  const int tid = threadIdx.x;
  const int lane = tid & 63, rr = tid >> 6;
#pragma unroll
  for (int p = 0; p < 16; ++p) {
    const int cl = p * 4 + rr;
    tile[cl][lane] = w[(size_t)(ct * 64 + cl) * 512 + it * 64 + lane];
  }
  __syncthreads();
#pragma unroll
  for (int p = 0; p < 16; ++p) {
    const int il = p * 4 + rr;
    wt[(size_t)(it * 64 + il) * 512 + ct * 64 + lane] = __float2bfloat16(tile[lane][il]);
  }
}

__global__ __launch_bounds__(64)
void prep_bias(const float* __restrict__ wo, const float* __restrict__ bv,
               const float* __restrict__ bo, const float* __restrict__ bq,
               const float* __restrict__ bk,
               float* __restrict__ bvo, float* __restrict__ bqk)
{
  const int o = blockIdx.x * 64 + threadIdx.x;
  const float4* row = reinterpret_cast<const float4*>(wo + (size_t)o * 512);
  const float4* b4 = reinterpret_cast<const float4*>(bv);
  float s = 0.f;
#pragma unroll 8
  for (int i = 0; i < 128; ++i) {
    float4 a = row[i], b = b4[i];
    s += a.x * b.x + a.y * b.y + a.z * b.z + a.w * b.w;
  }
  bvo[o] = s + bo[o];
  bqk[o] = bq[o];
  bqk[512 + o] = bk[o];
}

// ---------------------------------------------------------------------------
extern "C" void kernel_launch(void* const* d_in, const int* in_sizes, int n_in,
                              void* d_out, int out_size, void* d_ws, size_t ws_size,
                              hipStream_t stream)
{
  const float* x   = (const float*)d_in[0];
  const float* gns = (const float*)d_in[1];
  const float* gnb = (const float*)d_in[2];
  const float* wq  = (const float*)d_in[3];
  const float* bq  = (const float*)d_in[4];
  const float* wk  = (const float*)d_in[5];
  const float* bk  = (const float*)d_in[6];
  const float* wv  = (const float*)d_in[7];
  const float* bv  = (const float*)d_in[8];
  const float* wo  = (const float*)d_in[9];
  const float* bo  = (const float*)d_in[10];
  float* out = (float*)d_out;

  const int WB = 512 * 512;
  const long long HT  = 4096LL * 512;
  const long long QKz = 4096LL * 1024;
  const long long VOz = 512LL * 4096;
  const long long SS  = 4096LL * 4096;
  const long long CHW = 512LL * 4096;

  char* base = (char*)d_ws;
  size_t off = 0;
  auto alloc = [&](size_t b) { void* r = base + off; off = (off + b + 255) & ~(size_t)255; return r; };

  __hip_bfloat16* wbf = (__hip_bfloat16*)alloc((size_t)5 * WB * 2);
  float* bqk   = (float*)alloc(1024 * 4);
  float* bvo   = (float*)alloc(512 * 4);
  float* part  = (float*)alloc(2 * 32 * 16 * 2 * 4);
  float* stats = (float*)alloc(2 * 32 * 2 * 4);
  float* rsum  = (float*)alloc(2 * 4096 * 4);
  float* part2 = (float*)alloc((size_t)2 * 16 * 4096 * 4);   // 512 KB
  const size_t fixed = off;

  const size_t qkB = (size_t)2 * QKz * 2;   // 16 MB
  const size_t voB = (size_t)2 * VOz * 2;   // 8 MB
  const size_t sB2 = (size_t)2 * SS * 2;    // 64 MB
  const size_t sB1 = (size_t)SS * 2;        // 32 MB
  const int MODE = (ws_size >= fixed + qkB + voB + sB2) ? 2 : 1;

  __hip_bfloat16* qk   = (__hip_bfloat16*)alloc(qkB);
  __hip_bfloat16* vo   = (__hip_bfloat16*)alloc(voB);
  const size_t sbufB = (MODE == 2) ? sB2 : sB1;
  __hip_bfloat16* sbuf = (__hip_bfloat16*)alloc(sbufB);
  // ht aliases the tail of sbuf: dead before S GEMM writes sbuf.
  __hip_bfloat16* ht = (__hip_bfloat16*)((char*)sbuf + sbufB - (size_t)2 * HT * 2);

  __hip_bfloat16* wqk = wbf;
  __hip_bfloat16* woB = wbf + 2 * WB;
  __hip_bfloat16* wvT = wbf + 3 * WB;
  __hip_bfloat16* wvo = wbf + 4 * WB;

  const float SC = 0.04419417382415922f;                 // 512^-0.5
  const float CEXP = SC * 1.4426950408889634f;           // for exp2

  cast3<<<dim3(256, 3), 256, 0, stream>>>(wq, wk, wo, wbf);
  transpose_cast<<<dim3(8, 8), 256, 0, stream>>>(wv, wvT);
  prep_bias<<<8, 64, 0, stream>>>(wo, bv, bo, bq, bk, bvo, bqk);
  gn_partial<<<dim3(32, 16, 2), 256, 0, stream>>>(x, part);
  gn_finalize<<<1, 64, 0, stream>>>(part, stats, 64);

  // WVO[o][i] = sum_c wo[o][c] * wvT[i][c]
  gemm_nt<0, 0, 0, 1, 0, 4, 0><<<dim3(4, 4, 1), 256, 0, stream>>>(
      woB, wvT, wvo, nullptr, nullptr, nullptr, 1.f, 512, 512, 512,
      512, 512, 512, 0, 0, 0, 0);

  gn_apply_t<<<dim3(64, 8, 2), 256, 0, stream>>>(x, stats, gns, gnb, ht);

  // [Q|K][s][o2] = ht . wqk^T + bqk
  gemm_nt<0, 2, 0, 1, 0, 4, 0><<<dim3(32, 8, 2), 256, 0, stream>>>(
      ht, wqk, qk, bqk, nullptr, nullptr, 1.f, 4096, 1024, 512,
      512, 512, 1024, HT, 0, QKz, 0);

  // VO[o][j] = WVO . ht^T   (64x128 tile, flat 512, SWZ=3)
  gemm_nt<0, 0, 0, 1, 3, 2, 0><<<dim3(512, 1, 1), 256, 0, stream>>>(
      wvo, ht, vo, nullptr, nullptr, nullptr, 1.f, 512, 4096, 512,
      512, 512, 4096, 0, HT, VOz, 0);

  if (MODE == 2) {
    // Punnorm = exp(scale * Q.K^T) + row partials  (8-phase, sparse vmcnt)
    s_gemm8<<<512, 512, 0, stream>>>(qk, sbuf, part2, CEXP);
    rs_final<<<32, 256, 0, stream>>>(part2, rsum);
    // out[o][i] = (sum_j VO[o][j] Punnorm[i][j]) * rsum[i] + bvo[o] + x[o][i]
    gemm_nt<1, 1, 1, 1, 3, 2, 1><<<dim3(512, 1, 1), 256, 0, stream>>>(
        vo, sbuf, out, bvo, x, rsum, 1.f, 512, 4096, 4096,
        4096, 4096, 4096, VOz, SS, CHW, CHW);
  } else {
    for (int z = 0; z < 2; ++z) {
      gemm_nt<0, 0, 0, 0, 0, 4, 0><<<dim3(32, 32, 1), 256, 0, stream>>>(
          qk + (size_t)z * QKz, qk + (size_t)z * QKz + 512, sbuf, nullptr, nullptr,
          nullptr, SC, 4096, 4096, 512, 1024, 1024, 4096, 0, 0, 0, 0);
      softmax_rows<<<dim3(4096, 1), 256, 0, stream>>>(sbuf, 0);
      gemm_nt<1, 1, 1, 1, 0, 2, 0><<<dim3(8, 32, 1), 256, 0, stream>>>(
          vo + (size_t)z * VOz, sbuf, out + (size_t)z * CHW, bvo, x + (size_t)z * CHW,
          nullptr, 1.f, 512, 4096, 4096, 4096, 4096, 4096, 0, 0, 0, 0);
    }
  }
}

// Round 11
// 155.395 us; speedup vs baseline: 1.1145x; 1.0038x over previous
//
#include <hip/hip_runtime.h>
#include <hip/hip_bf16.h>

// AttnBlock: GN -> QKV 1x1conv -> attention(n=4096,d=512) -> out-proj -> +x
// R11: s_gemm8 UN-PINNED (m141 lesson: 6x sched_barrier(0)/phase defeats the
// compiler scheduler -> LDS and MFMA serialize, 25% MfmaUtil). Now: only one
// sched_barrier(0) after each s_barrier; compiler-managed lgkm waits; vmcnt
// once per tile (counted, vmcnt(4): retires exactly next tile's 4 regions,
// keeps 2 in flight). Stage schedule re-ledgered: ph1: B0,B1(t+1);
// ph2: A0(t+2); ph4: A1(t+2) + vmcnt.

typedef __attribute__((ext_vector_type(8))) short short8_t;
typedef __attribute__((ext_vector_type(4))) short short4_t;
typedef __attribute__((ext_vector_type(4))) float f32x4;

__device__ __forceinline__ void gload16(const void* g, void* l) {
  __builtin_amdgcn_global_load_lds(
      (const __attribute__((address_space(1))) void*)g,
      (__attribute__((address_space(3))) void*)l, 16, 0, 0);
}

__device__ __forceinline__ short f2bf_bits(float f) {
  __hip_bfloat16 h = __float2bfloat16(f);
  return *reinterpret_cast<short*>(&h);
}
__device__ __forceinline__ float bfbits2f(short s) {
  union { unsigned int u; float f; } c;
  c.u = ((unsigned int)(unsigned short)s) << 16;
  return c.f;
}

// ---------------------------------------------------------------------------
// s_gemm8: Punnorm[i][j] = exp2(c * Q[i][:].K[j][:]) + per-(bn) row partials.
// 512 thr = 8 waves (2M x 4N). Tile 256x256, BK=64, 8 K-tiles, 4 phases each.
// Serpentine reads: (0,0)[A0+B0] (0,1)[B1] (1,1)[A1] (1,0)[B0].
// Stage: ph1: B0,B1(t+1) [t in 1..6]; ph2: A0(t+2) [t<6]; ph4: A1(t+2) [t<6].
// vmcnt(4) at end ph4 (t<6): retires exactly tile t+1's 4 regions, keeps
// A0/A1(t+2) in flight. t=6: vmcnt(0) (tail). Write-after-read: each stage
// lands >=1 barrier after its slot's last read (A0 read ph1, A1 ph3, B1 ph3,
// B0 ph4 of the buf's previous tile).
// ---------------------------------------------------------------------------
__global__ __launch_bounds__(512)
void s_gemm8(const __hip_bfloat16* __restrict__ qk,
             __hip_bfloat16* __restrict__ P, float* __restrict__ part2,
             float c)
{
  const long long QKz = 4096LL * 1024;
  const long long SS  = 4096LL * 4096;

  const int b = blockIdx.x;                 // 512 blocks: 16m x 16n x 2z
  const int bz = b >> 8;
  const int r = b & 255, xcd = r & 7, sl = r >> 3;
  const int bm = (xcd >> 1) * 4 + (sl & 3);
  const int bn = (xcd & 1) * 8 + (sl >> 2);

  const __hip_bfloat16* Aq = qk + (size_t)bz * QKz;
  const __hip_bfloat16* Bk = Aq + 512;

  const int tid = threadIdx.x;
  const int wid = tid >> 6, l = tid & 63;
  const int wrM = wid >> 2, wcN = wid & 3;
  const int lhi = l >> 4, llo = l & 15;

  __shared__ char sm[2 * 65536];            // [buf][A 32KB | B 32KB]

  f32x4 acc[2][2][4][2] = {};               // [Mh][Nh][m][n]
  short8_t af[4][2], bf[2][2];              // persistent fragments

  const int rIn = l >> 3;
  const int colSw = 8 * ((l & 7) ^ (rIn & 7));
  const __hip_bfloat16* gA = Aq + (size_t)(bm * 256 + rIn) * 1024 + colSw;
  const __hip_bfloat16* gB = Bk + (size_t)(bn * 256 + rIn) * 1024 + colSw;

  auto STG = [&](int mat, int half, int t) {
    const __hip_bfloat16* src = mat ? gB : gA;
    char* dst = sm + (t & 1) * 65536 + mat * 32768;
    const int rb = half * 128 + wid * 16;
    gload16(src + (size_t)rb * 1024 + t * 64, dst + rb * 128);
    gload16(src + (size_t)(rb + 8) * 1024 + t * 64, dst + (rb + 8) * 128);
  };

#define PHASE(MH, NH, LA, LB, VM, ...) do {                                   \
    const char* bbA = sm + bsel * 65536;                                      \
    const char* bbB = bbA + 32768;                                            \
    if (LA) {                                                                 \
      _Pragma("unroll") for (int m = 0; m < 4; ++m) {                         \
        const int rowA = (MH) * 128 + wrM * 64 + m * 16 + llo;                \
        _Pragma("unroll") for (int kk = 0; kk < 2; ++kk)                      \
          af[m][kk] = *(const short8_t*)(bbA + rowA * 128 +                   \
                        (((kk * 4 + lhi) ^ (rowA & 7)) * 16));                \
      }                                                                       \
    }                                                                         \
    if (LB) {                                                                 \
      _Pragma("unroll") for (int n = 0; n < 2; ++n) {                         \
        const int rowB = (NH) * 128 + wcN * 32 + n * 16 + llo;                \
        _Pragma("unroll") for (int kk = 0; kk < 2; ++kk)                      \
          bf[n][kk] = *(const short8_t*)(bbB + rowB * 128 +                   \
                        (((kk * 4 + lhi) ^ (rowB & 7)) * 16));                \
      }                                                                       \
    }                                                                         \
    __VA_ARGS__;                                                              \
    __builtin_amdgcn_s_barrier();                                             \
    __builtin_amdgcn_sched_barrier(0);                                        \
    __builtin_amdgcn_s_setprio(1);                                            \
    _Pragma("unroll") for (int kk = 0; kk < 2; ++kk)                          \
      _Pragma("unroll") for (int m = 0; m < 4; ++m)                           \
        _Pragma("unroll") for (int n = 0; n < 2; ++n)                         \
          acc[MH][NH][m][n] = __builtin_amdgcn_mfma_f32_16x16x32_bf16(        \
              af[m][kk], bf[n][kk], acc[MH][NH][m][n], 0, 0, 0);              \
    __builtin_amdgcn_s_setprio(0);                                            \
    if ((VM) == 1) asm volatile("s_waitcnt vmcnt(4)" ::: "memory");           \
    if ((VM) == 2) asm volatile("s_waitcnt vmcnt(0)" ::: "memory");           \
    __builtin_amdgcn_s_barrier();                                             \
    __builtin_amdgcn_sched_barrier(0);                                        \
  } while (0)

  // prologue: tiles 0 (buf0) and 1 (buf1) fully staged, then drain once
  STG(0, 0, 0); STG(1, 0, 0); STG(0, 1, 0); STG(1, 1, 0);
  STG(0, 0, 1); STG(1, 0, 1); STG(0, 1, 1); STG(1, 1, 1);
  asm volatile("s_waitcnt vmcnt(0)" ::: "memory");
  __builtin_amdgcn_s_barrier();
  __builtin_amdgcn_sched_barrier(0);

  for (int t = 0; t < 8; ++t) {
    const int bsel = t & 1;
    const int stB = (t >= 1 && t < 7);      // stage B halves of t+1
    const int stA = (t < 6);                // stage A halves of t+2
    const int vm = (t < 6) ? 1 : (t == 6) ? 2 : 0;
    PHASE(0, 0, 1, 1, 0, if (stB) { STG(1, 0, t + 1); STG(1, 1, t + 1); });
    PHASE(0, 1, 0, 1, 0, if (stA) STG(0, 0, t + 2););
    PHASE(1, 1, 1, 0, 0, );
    PHASE(1, 0, 0, 1, vm, if (stA) STG(0, 1, t + 2););
  }
#undef PHASE

  // epilogue: store exp2 + row partials. C/D: col=lane&15, row=(lane>>4)*4+reg
  __hip_bfloat16* Pb = P + (size_t)bz * SS;
  float rp[2][4][4];                        // [Mh][m][rr] per-lane row partial
#pragma unroll
  for (int Mh = 0; Mh < 2; ++Mh)
#pragma unroll
    for (int m = 0; m < 4; ++m)
#pragma unroll
      for (int rr = 0; rr < 4; ++rr) {
        const int grow = bm * 256 + Mh * 128 + wrM * 64 + m * 16 + lhi * 4 + rr;
        float s = 0.f;
#pragma unroll
        for (int Nh = 0; Nh < 2; ++Nh)
#pragma unroll
          for (int n = 0; n < 2; ++n) {
            const int gcol = bn * 256 + Nh * 128 + wcN * 32 + n * 16 + llo;
            const float v = exp2f(acc[Mh][Nh][m][n][rr] * c);
            Pb[(size_t)grow * 4096 + gcol] = __float2bfloat16(v);
            s += v;
          }
        rp[Mh][m][rr] = s;
      }
  // reduce across llo (lane bits 0..3)
#pragma unroll
  for (int Mh = 0; Mh < 2; ++Mh)
#pragma unroll
    for (int m = 0; m < 4; ++m)
#pragma unroll
      for (int rr = 0; rr < 4; ++rr) {
        float s = rp[Mh][m][rr];
        s += __shfl_xor(s, 1); s += __shfl_xor(s, 2);
        s += __shfl_xor(s, 4); s += __shfl_xor(s, 8);
        rp[Mh][m][rr] = s;
      }
  __syncthreads();                          // safe to reuse sm
  float* rsl = (float*)sm;                  // [256][4]
  if (llo == 0) {
#pragma unroll
    for (int Mh = 0; Mh < 2; ++Mh)
#pragma unroll
      for (int m = 0; m < 4; ++m)
#pragma unroll
        for (int rr = 0; rr < 4; ++rr) {
          const int rl = Mh * 128 + wrM * 64 + m * 16 + lhi * 4 + rr;
          rsl[rl * 4 + wcN] = rp[Mh][m][rr];
        }
  }
  __syncthreads();
  if (tid < 256) {
    const float s = rsl[tid * 4] + rsl[tid * 4 + 1] + rsl[tid * 4 + 2] + rsl[tid * 4 + 3];
    part2[((size_t)bz * 16 + bn) * 4096 + bm * 256 + tid] = s;
  }
}

// rs[z][row] = 1 / sum_bn part2[z][bn][row].  8192 threads.
__global__ __launch_bounds__(256)
void rs_final(const float* __restrict__ part2, float* __restrict__ rs)
{
  const int i = blockIdx.x * 256 + threadIdx.x;  // 0..8191
  const int z = i >> 12, row = i & 4095;
  float s = 0.f;
#pragma unroll
  for (int bn = 0; bn < 16; ++bn)
    s += part2[((size_t)z * 16 + bn) * 4096 + row];
  rs[(size_t)z * 4096 + row] = 1.f / s;
}

// ---------------------------------------------------------------------------
// R5-proven 4-wave NT GEMM. NORM: multiply by rnorm[z*4096+gcol] (PV MODE2).
// ---------------------------------------------------------------------------
template<int OUTF, int BIASMODE, int RESID, int PIPE, int SWZ, int MF, int NORM>
__global__ __launch_bounds__(256, 2)
void gemm_nt(const __hip_bfloat16* __restrict__ A,
             const __hip_bfloat16* __restrict__ B,
             void* __restrict__ Cv,
             const float* __restrict__ bias,
             const float* __restrict__ resid,
             const float* __restrict__ rnorm,
             float scale, int M, int N, int K,
             int lda, int ldb, int ldc,
             long long strA, long long strB, long long strC, long long strR)
{
  int bm, bn, bz;
  if (SWZ == 0) {
    bm = blockIdx.x; bn = blockIdx.y; bz = blockIdx.z;
  } else if (SWZ == 2) {
    const int b = blockIdx.x;            // 2048 blocks
    bz = b >> 10;
    const int b2 = b & 1023;
    const int xcd = b2 & 7, s = b2 >> 3;
    bm = (xcd >> 1) * 8 + (s & 7);
    bn = (xcd & 1) * 16 + (s >> 3);
  } else {
    const int b = blockIdx.x;                 // 512 blocks (8m x 32n x 2z)
    const int xcd = b & 7, slot = b >> 3;
    bm = slot & 7;
    const int panel = xcd * 8 + (slot >> 3);
    bn = panel & 31; bz = panel >> 5;
  }
  const int z = bz;
  A += (size_t)z * strA;
  B += (size_t)z * strB;

  const int tid = threadIdx.x;
  const int w = tid >> 6, l = tid & 63;
  const int wr = w >> 1, wc = w & 1;
  const int lhi = l >> 4, llo = l & 15;
  const int m0 = bm * (MF * 32), n0 = bn * 128;

  constexpr int BUFSZ = MF * 4096 + 16384;
  __shared__ char sm[(PIPE ? 2 : 1) * BUFSZ];

  f32x4 acc[MF][4] = {};

  const int rowInCh = l >> 3;
  const int colOff = 8 * ((l & 7) ^ (rowInCh & 7));

  const __hip_bfloat16* gAr[MF];
  const __hip_bfloat16* gBr[4];
#pragma unroll
  for (int j = 0; j < MF; ++j)
    gAr[j] = A + (size_t)(m0 + w * (8 * MF) + j * 8 + rowInCh) * lda + colOff;
#pragma unroll
  for (int r = 0; r < 4; ++r)
    gBr[r] = B + (size_t)(n0 + w * 32 + r * 8 + rowInCh) * ldb + colOff;

  auto stage = [&](int kt, int buf) {
    char* sA = sm + buf * BUFSZ;
    char* sB = sA + MF * 4096;
    const int ko = kt * 64;
#pragma unroll
    for (int j = 0; j < MF; ++j)
      gload16(gAr[j] + ko, sA + (w * MF + j) * 1024);
#pragma unroll
    for (int r = 0; r < 4; ++r)
      gload16(gBr[r] + ko, sB + (w * 4 + r) * 1024);
  };

  auto compute = [&](int buf) {
    char* sA = sm + buf * BUFSZ;
    char* sB = sA + MF * 4096;
#pragma unroll
    for (int kk = 0; kk < 2; ++kk) {
      short8_t af[MF], bfv[4];
#pragma unroll
      for (int m = 0; m < MF; ++m) {
        const int row = wr * (16 * MF) + m * 16 + llo;
        const int inner = ((kk * 4 + lhi) ^ (row & 7)) * 16;
        af[m] = *(const short8_t*)(sA + row * 128 + inner);
      }
#pragma unroll
      for (int n = 0; n < 4; ++n) {
        const int row = wc * 64 + n * 16 + llo;
        const int inner = ((kk * 4 + lhi) ^ (row & 7)) * 16;
        bfv[n] = *(const short8_t*)(sB + row * 128 + inner);
      }
#pragma unroll
      for (int m = 0; m < MF; ++m)
#pragma unroll
        for (int n = 0; n < 4; ++n)
          acc[m][n] = __builtin_amdgcn_mfma_f32_16x16x32_bf16(af[m], bfv[n], acc[m][n], 0, 0, 0);
    }
  };

  const int nkt = K >> 6;
  if (PIPE) {
    stage(0, 0);
    __syncthreads();
    int cur = 0;
    for (int kt = 0; kt < nkt; ++kt) {
      if (kt + 1 < nkt) stage(kt + 1, cur ^ 1);
      compute(cur);
      __syncthreads();
      cur ^= 1;
    }
  } else {
    for (int kt = 0; kt < nkt; ++kt) {
      __syncthreads();
      stage(kt, 0);
      __syncthreads();
      compute(0);
    }
  }

#pragma unroll
  for (int m = 0; m < MF; ++m) {
#pragma unroll
    for (int r = 0; r < 4; ++r) {
      const int grow = m0 + wr * (16 * MF) + m * 16 + lhi * 4 + r;
#pragma unroll
      for (int n = 0; n < 4; ++n) {
        const int gcol = n0 + wc * 64 + n * 16 + llo;
        float v = acc[m][n][r] * scale;
        if (NORM) v *= rnorm[(size_t)z * 4096 + gcol];
        if (BIASMODE == 1) v += bias[grow];
        if (BIASMODE == 2) v += bias[gcol];
        const size_t idx = (size_t)z * strC + (size_t)grow * ldc + gcol;
        if (RESID) v += resid[(size_t)z * strR + (size_t)grow * ldc + gcol];
        if (OUTF == 0) ((__hip_bfloat16*)Cv)[idx] = __float2bfloat16(v);
        else           ((float*)Cv)[idx] = v;
      }
    }
  }
}

// ---------------------------------------------------------------------------
__global__ __launch_bounds__(256)
void gn_partial(const float* __restrict__ x, float* __restrict__ part)
{
  const int g = blockIdx.x, sl = blockIdx.y, z = blockIdx.z;
  const int tid = threadIdx.x;
  const float* xf = x + (size_t)z * 512 * 4096 + (size_t)g * 16 * 4096 + (size_t)sl * 4096;
  const float4* px = reinterpret_cast<const float4*>(xf);
  float s = 0.f, q = 0.f;
#pragma unroll
  for (int i = 0; i < 4; ++i) {
    float4 v = px[tid + i * 256];
    s += v.x + v.y + v.z + v.w;
    q += v.x * v.x + v.y * v.y + v.z * v.z + v.w * v.w;
  }
#pragma unroll
  for (int o = 32; o; o >>= 1) { s += __shfl_xor(s, o); q += __shfl_xor(q, o); }
  __shared__ float rs[4], rq[4];
  if ((tid & 63) == 0) { rs[tid >> 6] = s; rq[tid >> 6] = q; }
  __syncthreads();
  if (tid == 0) {
    s = rs[0] + rs[1] + rs[2] + rs[3];
    q = rq[0] + rq[1] + rq[2] + rq[3];
    part[(((size_t)z * 32 + g) * 16 + sl) * 2 + 0] = s;
    part[(((size_t)z * 32 + g) * 16 + sl) * 2 + 1] = q;
  }
}

__global__ __launch_bounds__(64)
void gn_finalize(const float* __restrict__ part, float* __restrict__ stats, int n)
{
  const int i = threadIdx.x;
  if (i >= n) return;
  float s = 0.f, q = 0.f;
#pragma unroll
  for (int sl = 0; sl < 16; ++sl) {
    s += part[(i * 16 + sl) * 2 + 0];
    q += part[(i * 16 + sl) * 2 + 1];
  }
  const float mean = s * (1.0f / 65536.0f);
  const float var = q * (1.0f / 65536.0f) - mean * mean;
  stats[i * 2 + 0] = mean;
  stats[i * 2 + 1] = rsqrtf(var + 1e-6f);
}

__global__ __launch_bounds__(256)
void gn_apply_t(const float* __restrict__ x, const float* __restrict__ stats,
                const float* __restrict__ gns, const float* __restrict__ gnb,
                __hip_bfloat16* __restrict__ ht)
{
  const int st = blockIdx.x, ct = blockIdx.y, z = blockIdx.z;
  const int tid = threadIdx.x;
  __shared__ float tile[64][65];
  const float* xb = x + (size_t)z * 512 * 4096;
  const int lane64 = tid & 63, rr = tid >> 6;
#pragma unroll
  for (int pp = 0; pp < 16; ++pp) {
    const int cl = pp * 4 + rr;
    const int c = ct * 64 + cl;
    const int g = c >> 4;
    const float mean = stats[(z * 32 + g) * 2 + 0];
    const float rstd = stats[(z * 32 + g) * 2 + 1];
    const float val = xb[(size_t)c * 4096 + st * 64 + lane64];
    tile[cl][lane64] = (val - mean) * rstd * gns[c] + gnb[c];
  }
  __syncthreads();
  __hip_bfloat16* hb = ht + (size_t)z * 4096 * 512;
#pragma unroll
  for (int pp = 0; pp < 16; ++pp) {
    const int sl = pp * 4 + rr;
    const int s = st * 64 + sl;
    hb[(size_t)s * 512 + ct * 64 + lane64] = __float2bfloat16(tile[lane64][sl]);
  }
}

__global__ __launch_bounds__(256)
void softmax_rows(__hip_bfloat16* __restrict__ S, long long strZ)
{
  const int row = blockIdx.x, z = blockIdx.y;
  __hip_bfloat16* p = S + (size_t)z * strZ + (size_t)row * 4096;
  const int tid = threadIdx.x;
  short8_t a = *(const short8_t*)(p + tid * 16);
  short8_t b = *(const short8_t*)(p + tid * 16 + 8);
  float v[16];
#pragma unroll
  for (int i = 0; i < 8; ++i) { v[i] = bfbits2f(a[i]); v[8 + i] = bfbits2f(b[i]); }
  float m = v[0];
#pragma unroll
  for (int i = 1; i < 16; ++i) m = fmaxf(m, v[i]);
#pragma unroll
  for (int o = 32; o; o >>= 1) m = fmaxf(m, __shfl_xor(m, o));
  __shared__ float red[8];
  if ((tid & 63) == 0) red[tid >> 6] = m;
  __syncthreads();
  m = fmaxf(fmaxf(red[0], red[1]), fmaxf(red[2], red[3]));
  float s = 0.f;
#pragma unroll
  for (int i = 0; i < 16; ++i) { v[i] = exp2f((v[i] - m) * 1.44269504f); s += v[i]; }
#pragma unroll
  for (int o = 32; o; o >>= 1) s += __shfl_xor(s, o);
  __syncthreads();
  if ((tid & 63) == 0) red[4 + (tid >> 6)] = s;
  __syncthreads();
  s = red[4] + red[5] + red[6] + red[7];
  const float inv = 1.f / s;
#pragma unroll
  for (int i = 0; i < 8; ++i) { a[i] = f2bf_bits(v[i] * inv); b[i] = f2bf_bits(v[8 + i] * inv); }
  *(short8_t*)(p + tid * 16) = a;
  *(short8_t*)(p + tid * 16 + 8) = b;
}

__global__ __launch_bounds__(256)
void cast3(const float* __restrict__ w0, const float* __restrict__ w1,
           const float* __restrict__ w2, __hip_bfloat16* __restrict__ out)
{
  const int j = blockIdx.y;
  const float* src = (j == 0) ? w0 : (j == 1) ? w1 : w2;
  const int i = blockIdx.x * 256 + threadIdx.x;
  float4 v = reinterpret_cast<const float4*>(src)[i];
  short4_t o;
  o[0] = f2bf_bits(v.x); o[1] = f2bf_bits(v.y);
  o[2] = f2bf_bits(v.z); o[3] = f2bf_bits(v.w);
  *reinterpret_cast<short4_t*>((short*)out + (size_t)j * 262144 + (size_t)i * 4) = o;
}

__global__ __launch_bounds__(256)
void transpose_cast(const float* __restrict__ w, __hip_bfloat16* __restrict__ wt)
{
  __shared__ float tile[64][65];
  const int ct = blockIdx.x, it = blockIdx.y;
  const int tid = threadIdx.x;
  const int lane = tid & 63, rr = tid >> 6;
#pragma unroll
  for (int p = 0; p < 16; ++p) {
    const int cl = p * 4 + rr;
    tile[cl][lane] = w[(size_t)(ct * 64 + cl) * 512 + it * 64 + lane];
  }
  __syncthreads();
#pragma unroll
  for (int p = 0; p < 16; ++p) {
    const int il = p * 4 + rr;
    wt[(size_t)(it * 64 + il) * 512 + ct * 64 + lane] = __float2bfloat16(tile[lane][il]);
  }
}

__global__ __launch_bounds__(64)
void prep_bias(const float* __restrict__ wo, const float* __restrict__ bv,
               const float* __restrict__ bo, const float* __restrict__ bq,
               const float* __restrict__ bk,
               float* __restrict__ bvo, float* __restrict__ bqk)
{
  const int o = blockIdx.x * 64 + threadIdx.x;
  const float4* row = reinterpret_cast<const float4*>(wo + (size_t)o * 512);
  const float4* b4 = reinterpret_cast<const float4*>(bv);
  float s = 0.f;
#pragma unroll 8
  for (int i = 0; i < 128; ++i) {
    float4 a = row[i], b = b4[i];
    s += a.x * b.x + a.y * b.y + a.z * b.z + a.w * b.w;
  }
  bvo[o] = s + bo[o];
  bqk[o] = bq[o];
  bqk[512 + o] = bk[o];
}

// ---------------------------------------------------------------------------
extern "C" void kernel_launch(void* const* d_in, const int* in_sizes, int n_in,
                              void* d_out, int out_size, void* d_ws, size_t ws_size,
                              hipStream_t stream)
{
  const float* x   = (const float*)d_in[0];
  const float* gns = (const float*)d_in[1];
  const float* gnb = (const float*)d_in[2];
  const float* wq  = (const float*)d_in[3];
  const float* bq  = (const float*)d_in[4];
  const float* wk  = (const float*)d_in[5];
  const float* bk  = (const float*)d_in[6];
  const float* wv  = (const float*)d_in[7];
  const float* bv  = (const float*)d_in[8];
  const float* wo  = (const float*)d_in[9];
  const float* bo  = (const float*)d_in[10];
  float* out = (float*)d_out;

  const int WB = 512 * 512;
  const long long HT  = 4096LL * 512;
  const long long QKz = 4096LL * 1024;
  const long long VOz = 512LL * 4096;
  const long long SS  = 4096LL * 4096;
  const long long CHW = 512LL * 4096;

  char* base = (char*)d_ws;
  size_t off = 0;
  auto alloc = [&](size_t b) { void* r = base + off; off = (off + b + 255) & ~(size_t)255; return r; };

  __hip_bfloat16* wbf = (__hip_bfloat16*)alloc((size_t)5 * WB * 2);
  float* bqk   = (float*)alloc(1024 * 4);
  float* bvo   = (float*)alloc(512 * 4);
  float* part  = (float*)alloc(2 * 32 * 16 * 2 * 4);
  float* stats = (float*)alloc(2 * 32 * 2 * 4);
  float* rsum  = (float*)alloc(2 * 4096 * 4);
  float* part2 = (float*)alloc((size_t)2 * 16 * 4096 * 4);   // 512 KB
  const size_t fixed = off;

  const size_t qkB = (size_t)2 * QKz * 2;   // 16 MB
  const size_t voB = (size_t)2 * VOz * 2;   // 8 MB
  const size_t sB2 = (size_t)2 * SS * 2;    // 64 MB
  const size_t sB1 = (size_t)SS * 2;        // 32 MB
  const int MODE = (ws_size >= fixed + qkB + voB + sB2) ? 2 : 1;

  __hip_bfloat16* qk   = (__hip_bfloat16*)alloc(qkB);
  __hip_bfloat16* vo   = (__hip_bfloat16*)alloc(voB);
  const size_t sbufB = (MODE == 2) ? sB2 : sB1;
  __hip_bfloat16* sbuf = (__hip_bfloat16*)alloc(sbufB);
  // ht aliases the tail of sbuf: dead before S GEMM writes sbuf.
  __hip_bfloat16* ht = (__hip_bfloat16*)((char*)sbuf + sbufB - (size_t)2 * HT * 2);

  __hip_bfloat16* wqk = wbf;
  __hip_bfloat16* woB = wbf + 2 * WB;
  __hip_bfloat16* wvT = wbf + 3 * WB;
  __hip_bfloat16* wvo = wbf + 4 * WB;

  const float SC = 0.04419417382415922f;                 // 512^-0.5
  const float CEXP = SC * 1.4426950408889634f;           // for exp2

  cast3<<<dim3(256, 3), 256, 0, stream>>>(wq, wk, wo, wbf);
  transpose_cast<<<dim3(8, 8), 256, 0, stream>>>(wv, wvT);
  prep_bias<<<8, 64, 0, stream>>>(wo, bv, bo, bq, bk, bvo, bqk);
  gn_partial<<<dim3(32, 16, 2), 256, 0, stream>>>(x, part);
  gn_finalize<<<1, 64, 0, stream>>>(part, stats, 64);

  // WVO[o][i] = sum_c wo[o][c] * wvT[i][c]
  gemm_nt<0, 0, 0, 1, 0, 4, 0><<<dim3(4, 4, 1), 256, 0, stream>>>(
      woB, wvT, wvo, nullptr, nullptr, nullptr, 1.f, 512, 512, 512,
      512, 512, 512, 0, 0, 0, 0);

  gn_apply_t<<<dim3(64, 8, 2), 256, 0, stream>>>(x, stats, gns, gnb, ht);

  // [Q|K][s][o2] = ht . wqk^T + bqk
  gemm_nt<0, 2, 0, 1, 0, 4, 0><<<dim3(32, 8, 2), 256, 0, stream>>>(
      ht, wqk, qk, bqk, nullptr, nullptr, 1.f, 4096, 1024, 512,
      512, 512, 1024, HT, 0, QKz, 0);

  // VO[o][j] = WVO . ht^T   (64x128 tile, flat 512, SWZ=3)
  gemm_nt<0, 0, 0, 1, 3, 2, 0><<<dim3(512, 1, 1), 256, 0, stream>>>(
      wvo, ht, vo, nullptr, nullptr, nullptr, 1.f, 512, 4096, 512,
      512, 512, 4096, 0, HT, VOz, 0);

  if (MODE == 2) {
    // Punnorm = exp(scale * Q.K^T) + row partials  (8-phase, un-pinned)
    s_gemm8<<<512, 512, 0, stream>>>(qk, sbuf, part2, CEXP);
    rs_final<<<32, 256, 0, stream>>>(part2, rsum);
    // out[o][i] = (sum_j VO[o][j] Punnorm[i][j]) * rsum[i] + bvo[o] + x[o][i]
    gemm_nt<1, 1, 1, 1, 3, 2, 1><<<dim3(512, 1, 1), 256, 0, stream>>>(
        vo, sbuf, out, bvo, x, rsum, 1.f, 512, 4096, 4096,
        4096, 4096, 4096, VOz, SS, CHW, CHW);
  } else {
    for (int z = 0; z < 2; ++z) {
      gemm_nt<0, 0, 0, 0, 0, 4, 0><<<dim3(32, 32, 1), 256, 0, stream>>>(
          qk + (size_t)z * QKz, qk + (size_t)z * QKz + 512, sbuf, nullptr, nullptr,
          nullptr, SC, 4096, 4096, 512, 1024, 1024, 4096, 0, 0, 0, 0);
      softmax_rows<<<dim3(4096, 1), 256, 0, stream>>>(sbuf, 0);
      gemm_nt<1, 1, 1, 1, 0, 2, 0><<<dim3(8, 32, 1), 256, 0, stream>>>(
          vo + (size_t)z * VOz, sbuf, out + (size_t)z * CHW, bvo, x + (size_t)z * CHW,
          nullptr, 1.f, 512, 4096, 4096, 4096, 4096, 4096, 0, 0, 0, 0);
    }
  }
}